// Round 3
// baseline (486.108 us; speedup 1.0000x reference)
//
#include <hip/hip_runtime.h>
#include <math.h>

#define Bsz  16
#define CIN  64
#define LEN  1024
#define HIDN 1024
#define OUTN 512
#define MTOT (Bsz*LEN)   // 16384
#define KTOT (3*HIDN)    // 3072

typedef __attribute__((ext_vector_type(8))) short bf16x8;
typedef __attribute__((ext_vector_type(16))) float f32x16;

__device__ __forceinline__ unsigned short f2bf(float x) {
    union { float f; unsigned int u; } v; v.f = x;
    unsigned int r = v.u + 0x7fff + ((v.u >> 16) & 1);   // RNE
    return (unsigned short)(r >> 16);
}
__device__ __forceinline__ float bf2f(unsigned short u) {
    union { unsigned int u; float f; } v; v.u = ((unsigned int)u) << 16;
    return v.f;
}
__device__ __forceinline__ void gload_lds16(const void* g, void* l) {
    // width=16 async global->LDS; LDS dest = wave-uniform base + lane*16
    __builtin_amdgcn_global_load_lds((const __attribute__((address_space(1))) void*)g,
                                     (__attribute__((address_space(3))) void*)l, 16, 0, 0);
}

// ---------------- prep: coeffs (NOUT,HIDN,4) -> WT[o][k] bf16 (k = i*HIDN + c, i=1..3)
// and beff[o] = bias[o] + sum_c coeffs[o][c][0]
__global__ __launch_bounds__(256) void prep_w(const float* __restrict__ coeffs,
                                              const float* __restrict__ bias,
                                              unsigned short* __restrict__ WT,
                                              float* __restrict__ beff) {
    int o = blockIdx.x, t = threadIdx.x;
    float s = 0.f;
    unsigned short* wrow = WT + (size_t)o * KTOT;
    for (int c = t; c < HIDN; c += 256) {
        float4 v = *(const float4*)(coeffs + ((size_t)o * HIDN + c) * 4);
        s += v.x;
        wrow[c]            = f2bf(v.y);
        wrow[HIDN + c]     = f2bf(v.z);
        wrow[2 * HIDN + c] = f2bf(v.w);
    }
    __shared__ float red[4];
    for (int off = 32; off > 0; off >>= 1) s += __shfl_down(s, off, 64);
    if ((t & 63) == 0) red[t >> 6] = s;
    __syncthreads();
    if (t == 0) beff[o] = bias[o] + red[0] + red[1] + red[2] + red[3];
}

// ---------------- proj_in: h = x @ Win + bin, emit bf16 powers [h, h^2, h^3]
// thread t owns 4 consecutive hidden cols (4t..4t+3) -> float4 W loads, ushort4 stores
__global__ __launch_bounds__(256) void proj_in(const float* __restrict__ x,
                                               const float* __restrict__ Win,
                                               const float* __restrict__ bin,
                                               unsigned short* __restrict__ Hpow) {
    __shared__ float xs[CIN][17];
    int t = threadIdx.x;
    int m0 = blockIdx.x * 16;
    int b = m0 >> 10, l0 = m0 & 1023;
    for (int idx = t; idx < CIN * 16; idx += 256) {
        int c = idx >> 4, r = idx & 15;
        xs[c][r] = x[((size_t)b * CIN + c) * LEN + l0 + r];
    }
    __syncthreads();
    float acc[16][4];
#pragma unroll
    for (int r = 0; r < 16; r++)
#pragma unroll
        for (int j = 0; j < 4; j++) acc[r][j] = 0.f;
    for (int c = 0; c < CIN; c++) {
        float4 w = *(const float4*)(Win + (size_t)c * HIDN + 4 * t);
#pragma unroll
        for (int r = 0; r < 16; r++) {
            float xv = xs[c][r];
            acc[r][0] += xv * w.x; acc[r][1] += xv * w.y;
            acc[r][2] += xv * w.z; acc[r][3] += xv * w.w;
        }
    }
    float4 bb = *(const float4*)(bin + 4 * t);
    for (int r = 0; r < 16; r++) {
        unsigned short* dst = Hpow + (size_t)(m0 + r) * KTOT + 4 * t;
        float h0 = acc[r][0] + bb.x, h1 = acc[r][1] + bb.y;
        float h2 = acc[r][2] + bb.z, h3 = acc[r][3] + bb.w;
        ushort4 p1 = { f2bf(h0), f2bf(h1), f2bf(h2), f2bf(h3) };
        ushort4 p2 = { f2bf(h0*h0), f2bf(h1*h1), f2bf(h2*h2), f2bf(h3*h3) };
        ushort4 p3 = { f2bf(h0*h0*h0), f2bf(h1*h1*h1), f2bf(h2*h2*h2), f2bf(h3*h3*h3) };
        *(ushort4*)(dst)            = p1;
        *(ushort4*)(dst + HIDN)     = p2;
        *(ushort4*)(dst + 2*HIDN)   = p3;
    }
}

// ---------------- MFMA GEMM (32x32x16): Y[M][N] = A(M x 3072) @ BT(N x 3072)^T + beff
// BM=BN=128, BK=64; 4 waves, each a 64x64 quadrant = 2x2 of 32x32 MFMA tiles.
template<int N, bool BF16OUT>
__global__ __launch_bounds__(256) void mfma_gemm(const unsigned short* __restrict__ A,
                                                 const unsigned short* __restrict__ BT,
                                                 const float* __restrict__ beff,
                                                 void* __restrict__ Yv) {
    __shared__ unsigned short As[128 * 64];   // chunk(r,cc) holds global chunk (r, cc ^ (r&7))
    __shared__ unsigned short Bs[128 * 64];
    int t = threadIdx.x;
    int lane = t & 63, wave = t >> 6;
    int m0 = blockIdx.x * 128, n0 = blockIdx.y * 128;
    const unsigned short* Ab = A + (size_t)m0 * KTOT;
    const unsigned short* Bb = BT + (size_t)n0 * KTOT;

    int srow = lane >> 3;                 // 0..7 within an 8-row staging group
    int sgcc = (lane & 7) ^ srow;         // swizzled global 16B-chunk column

    f32x16 acc[2][2] = {};
    int wr = (wave >> 1) * 64;            // wave's row offset in the 128-tile
    int wc = (wave & 1) * 64;
    int row32 = lane & 31, half = lane >> 5;

    for (int k0 = 0; k0 < KTOT; k0 += 64) {
#pragma unroll
        for (int j = 0; j < 4; j++) {
            int rgrp = wave * 32 + j * 8;   // wave-uniform
            gload_lds16(Ab + ((size_t)(rgrp + srow) * KTOT + k0 + sgcc * 8), As + rgrp * 64);
            gload_lds16(Bb + ((size_t)(rgrp + srow) * KTOT + k0 + sgcc * 8), Bs + rgrp * 64);
        }
        __syncthreads();
#pragma unroll
        for (int ks = 0; ks < 4; ks++) {
            int cidx = ks * 2 + half;       // 16B chunk index (k = cidx*8)
            bf16x8 af[2], bf[2];
#pragma unroll
            for (int mt = 0; mt < 2; mt++) {
                int r = wr + mt * 32 + row32;
                af[mt] = *(const bf16x8*)(As + r * 64 + ((cidx ^ (r & 7)) << 3));
            }
#pragma unroll
            for (int nt = 0; nt < 2; nt++) {
                int c = wc + nt * 32 + row32;
                bf[nt] = *(const bf16x8*)(Bs + c * 64 + ((cidx ^ (c & 7)) << 3));
            }
#pragma unroll
            for (int mt = 0; mt < 2; mt++)
#pragma unroll
                for (int nt = 0; nt < 2; nt++)
                    acc[mt][nt] = __builtin_amdgcn_mfma_f32_32x32x16_bf16(af[mt], bf[nt], acc[mt][nt], 0, 0, 0);
        }
        __syncthreads();
    }
    // epilogue: D layout col=lane&31, row=(reg&3)+8*(reg>>2)+4*half
#pragma unroll
    for (int nt = 0; nt < 2; nt++) {
        int oc = n0 + wc + nt * 32 + row32;
        float bo = beff[oc];
#pragma unroll
        for (int mt = 0; mt < 2; mt++) {
#pragma unroll
            for (int reg = 0; reg < 16; reg++) {
                int rl = (reg & 3) + 8 * (reg >> 2) + 4 * half;
                int mr = m0 + wr + mt * 32 + rl;
                float v = acc[mt][nt][reg] + bo;
                if (BF16OUT) ((unsigned short*)Yv)[(size_t)mr * N + oc] = f2bf(v);
                else         ((float*)Yv)[(size_t)mr * N + oc] = v;
            }
        }
    }
}

// ---------------- LN(1024) + exact GELU, emit bf16 powers [g, g^2, g^3]
// thread t owns 4 consecutive cols -> ushort4 loads/stores
__global__ __launch_bounds__(256) void ln_gelu(const unsigned short* __restrict__ y1,
                                               const float* __restrict__ g,
                                               const float* __restrict__ be,
                                               unsigned short* __restrict__ Gpow) {
    __shared__ float red[4];
    int m = blockIdx.x, t = threadIdx.x;
    const unsigned short* row = y1 + (size_t)m * HIDN;
    ushort4 u = *(const ushort4*)(row + 4 * t);
    float v[4] = { bf2f(u.x), bf2f(u.y), bf2f(u.z), bf2f(u.w) };
    float s = v[0] + v[1] + v[2] + v[3];
    for (int off = 32; off > 0; off >>= 1) s += __shfl_down(s, off, 64);
    if ((t & 63) == 0) red[t >> 6] = s;
    __syncthreads();
    float mu = (red[0] + red[1] + red[2] + red[3]) * (1.f / HIDN);
    __syncthreads();
    float ss = 0.f;
#pragma unroll
    for (int j = 0; j < 4; j++) { float d = v[j] - mu; ss += d * d; }
    for (int off = 32; off > 0; off >>= 1) ss += __shfl_down(ss, off, 64);
    if ((t & 63) == 0) red[t >> 6] = ss;
    __syncthreads();
    float rs = rsqrtf((red[0] + red[1] + red[2] + red[3]) * (1.f / HIDN) + 1e-5f);
    float4 gg = *(const float4*)(g + 4 * t);
    float4 bb = *(const float4*)(be + 4 * t);
    float gl[4];
    float gv[4] = { gg.x, gg.y, gg.z, gg.w };
    float bv[4] = { bb.x, bb.y, bb.z, bb.w };
#pragma unroll
    for (int j = 0; j < 4; j++) {
        float xn = (v[j] - mu) * rs * gv[j] + bv[j];
        gl[j] = xn * 0.5f * (1.f + erff(xn * 0.70710678118654752f));
    }
    unsigned short* dst = Gpow + (size_t)m * KTOT + 4 * t;
    ushort4 p1 = { f2bf(gl[0]), f2bf(gl[1]), f2bf(gl[2]), f2bf(gl[3]) };
    ushort4 p2 = { f2bf(gl[0]*gl[0]), f2bf(gl[1]*gl[1]), f2bf(gl[2]*gl[2]), f2bf(gl[3]*gl[3]) };
    ushort4 p3 = { f2bf(gl[0]*gl[0]*gl[0]), f2bf(gl[1]*gl[1]*gl[1]),
                   f2bf(gl[2]*gl[2]*gl[2]), f2bf(gl[3]*gl[3]*gl[3]) };
    *(ushort4*)(dst)          = p1;
    *(ushort4*)(dst + HIDN)   = p2;
    *(ushort4*)(dst + 2*HIDN) = p3;
}

// ---------------- LN(512) per row + mean over L -> out (atomics)
__global__ __launch_bounds__(256) void ln_pool(const float* __restrict__ y2,
                                               const float* __restrict__ g,
                                               const float* __restrict__ be,
                                               float* __restrict__ out) {
    __shared__ float red[4];
    int m = blockIdx.x, t = threadIdx.x;
    const float* row = y2 + (size_t)m * OUTN;
    float2 v = *(const float2*)(row + 2 * t);
    float s = v.x + v.y;
    for (int off = 32; off > 0; off >>= 1) s += __shfl_down(s, off, 64);
    if ((t & 63) == 0) red[t >> 6] = s;
    __syncthreads();
    float mu = (red[0] + red[1] + red[2] + red[3]) * (1.f / OUTN);
    __syncthreads();
    float d0 = v.x - mu, d1 = v.y - mu;
    float ss = d0 * d0 + d1 * d1;
    for (int off = 32; off > 0; off >>= 1) ss += __shfl_down(ss, off, 64);
    if ((t & 63) == 0) red[t >> 6] = ss;
    __syncthreads();
    float rs = rsqrtf((red[0] + red[1] + red[2] + red[3]) * (1.f / OUTN) + 1e-5f);
    float2 gg = *(const float2*)(g + 2 * t);
    float2 bb = *(const float2*)(be + 2 * t);
    int b = m >> 10;
    float val0 = (d0 * rs * gg.x + bb.x) * (1.f / LEN);
    float val1 = (d1 * rs * gg.y + bb.y) * (1.f / LEN);
    atomicAdd(out + (size_t)b * OUTN + 2 * t,     val0);
    atomicAdd(out + (size_t)b * OUTN + 2 * t + 1, val1);
}

extern "C" void kernel_launch(void* const* d_in, const int* in_sizes, int n_in,
                              void* d_out, int out_size, void* d_ws, size_t ws_size,
                              hipStream_t stream) {
    const float* x       = (const float*)d_in[0];
    const float* Win     = (const float*)d_in[1];
    const float* bin     = (const float*)d_in[2];
    const float* coeffs1 = (const float*)d_in[3];
    const float* bias1   = (const float*)d_in[4];
    const float* g1      = (const float*)d_in[5];
    const float* beta1   = (const float*)d_in[6];
    const float* coeffs2 = (const float*)d_in[7];
    const float* bias2   = (const float*)d_in[8];
    const float* g2      = (const float*)d_in[9];
    const float* beta2   = (const float*)d_in[10];
    float* out = (float*)d_out;

    char* ws = (char*)d_ws;
    unsigned short* Hpow = (unsigned short*)ws;                         // 100,663,296 B
    char* p1 = ws + (size_t)MTOT * KTOT * 2;
    unsigned short* y1   = (unsigned short*)p1;                         // 33,554,432 B
    float*          y2   = (float*)p1;                                  // alias (same size)
    char* p2 = p1 + (size_t)MTOT * HIDN * 2;
    unsigned short* W1T  = (unsigned short*)p2;                         // 6,291,456 B
    char* p3 = p2 + (size_t)HIDN * KTOT * 2;
    unsigned short* W2T  = (unsigned short*)p3;                         // 3,145,728 B
    char* p4 = p3 + (size_t)OUTN * KTOT * 2;
    float* b1e = (float*)p4;                                            // 4 KB
    float* b2e = (float*)(p4 + HIDN * sizeof(float));                   // 2 KB
    unsigned short* G2pow = Hpow;   // alias: Hpow dead after GEMM1

    hipMemsetAsync(d_out, 0, (size_t)out_size * sizeof(float), stream);
    prep_w<<<HIDN, 256, 0, stream>>>(coeffs1, bias1, W1T, b1e);
    prep_w<<<OUTN, 256, 0, stream>>>(coeffs2, bias2, W2T, b2e);
    proj_in<<<MTOT / 16, 256, 0, stream>>>(x, Win, bin, Hpow);
    mfma_gemm<HIDN, true><<<dim3(MTOT / 128, HIDN / 128), 256, 0, stream>>>(Hpow, W1T, b1e, y1);
    ln_gelu<<<MTOT, 256, 0, stream>>>(y1, g1, beta1, G2pow);
    mfma_gemm<OUTN, false><<<dim3(MTOT / 128, OUTN / 128), 256, 0, stream>>>(G2pow, W2T, b2e, y2);
    ln_pool<<<MTOT, 256, 0, stream>>>(y2, g2, beta2, out);
}

// Round 4
// 338.094 us; speedup vs baseline: 1.4378x; 1.4378x over previous
//
#include <hip/hip_runtime.h>
#include <math.h>

#define Bsz  16
#define CIN  64
#define LEN  1024
#define HIDN 1024
#define OUTN 512
#define MTOT (Bsz*LEN)   // 16384
#define KTOT (3*HIDN)    // 3072
#define LCHUNKS 32
#define LROWS   (LEN/LCHUNKS)  // 32 rows per block

typedef __attribute__((ext_vector_type(8))) short bf16x8;
typedef __attribute__((ext_vector_type(16))) float f32x16;

__device__ __forceinline__ unsigned short f2bf(float x) {
    union { float f; unsigned int u; } v; v.f = x;
    unsigned int r = v.u + 0x7fff + ((v.u >> 16) & 1);   // RNE
    return (unsigned short)(r >> 16);
}
__device__ __forceinline__ float bf2f(unsigned short u) {
    union { unsigned int u; float f; } v; v.u = ((unsigned int)u) << 16;
    return v.f;
}
__device__ __forceinline__ void gload_lds16(const void* g, void* l) {
    // width=16 async global->LDS; LDS dest = wave-uniform base + lane*16
    __builtin_amdgcn_global_load_lds((const __attribute__((address_space(1))) void*)g,
                                     (__attribute__((address_space(3))) void*)l, 16, 0, 0);
}

// ---------------- prep: coeffs (NOUT,HIDN,4) -> WT[o][k] bf16 (k = i*HIDN + c, i=1..3)
// and beff[o] = bias[o] + sum_c coeffs[o][c][0]
__global__ __launch_bounds__(256) void prep_w(const float* __restrict__ coeffs,
                                              const float* __restrict__ bias,
                                              unsigned short* __restrict__ WT,
                                              float* __restrict__ beff) {
    int o = blockIdx.x, t = threadIdx.x;
    float s = 0.f;
    unsigned short* wrow = WT + (size_t)o * KTOT;
    for (int c = t; c < HIDN; c += 256) {
        float4 v = *(const float4*)(coeffs + ((size_t)o * HIDN + c) * 4);
        s += v.x;
        wrow[c]            = f2bf(v.y);
        wrow[HIDN + c]     = f2bf(v.z);
        wrow[2 * HIDN + c] = f2bf(v.w);
    }
    __shared__ float red[4];
    for (int off = 32; off > 0; off >>= 1) s += __shfl_down(s, off, 64);
    if ((t & 63) == 0) red[t >> 6] = s;
    __syncthreads();
    if (t == 0) beff[o] = bias[o] + red[0] + red[1] + red[2] + red[3];
}

// ---------------- proj_in: h = x @ Win + bin, emit bf16 powers [h, h^2, h^3]
__global__ __launch_bounds__(256) void proj_in(const float* __restrict__ x,
                                               const float* __restrict__ Win,
                                               const float* __restrict__ bin,
                                               unsigned short* __restrict__ Hpow) {
    __shared__ float xs[CIN][17];
    int t = threadIdx.x;
    int m0 = blockIdx.x * 16;
    int b = m0 >> 10, l0 = m0 & 1023;
    for (int idx = t; idx < CIN * 16; idx += 256) {
        int c = idx >> 4, r = idx & 15;
        xs[c][r] = x[((size_t)b * CIN + c) * LEN + l0 + r];
    }
    __syncthreads();
    float acc[16][4];
#pragma unroll
    for (int r = 0; r < 16; r++)
#pragma unroll
        for (int j = 0; j < 4; j++) acc[r][j] = 0.f;
    for (int c = 0; c < CIN; c++) {
        float4 w = *(const float4*)(Win + (size_t)c * HIDN + 4 * t);
#pragma unroll
        for (int r = 0; r < 16; r++) {
            float xv = xs[c][r];
            acc[r][0] += xv * w.x; acc[r][1] += xv * w.y;
            acc[r][2] += xv * w.z; acc[r][3] += xv * w.w;
        }
    }
    float4 bb = *(const float4*)(bin + 4 * t);
    for (int r = 0; r < 16; r++) {
        unsigned short* dst = Hpow + (size_t)(m0 + r) * KTOT + 4 * t;
        float h0 = acc[r][0] + bb.x, h1 = acc[r][1] + bb.y;
        float h2 = acc[r][2] + bb.z, h3 = acc[r][3] + bb.w;
        ushort4 p1 = { f2bf(h0), f2bf(h1), f2bf(h2), f2bf(h3) };
        ushort4 p2 = { f2bf(h0*h0), f2bf(h1*h1), f2bf(h2*h2), f2bf(h3*h3) };
        ushort4 p3 = { f2bf(h0*h0*h0), f2bf(h1*h1*h1), f2bf(h2*h2*h2), f2bf(h3*h3*h3) };
        *(ushort4*)(dst)            = p1;
        *(ushort4*)(dst + HIDN)     = p2;
        *(ushort4*)(dst + 2*HIDN)   = p3;
    }
}

// ---------------- MFMA GEMM (32x32x16): Y[M][N] = A(M x 3072) @ BT(N x 3072)^T + beff
// BM=BN=128, BK=64; 4 waves, each a 64x64 quadrant = 2x2 of 32x32 MFMA tiles.
template<int N, bool BF16OUT>
__global__ __launch_bounds__(256) void mfma_gemm(const unsigned short* __restrict__ A,
                                                 const unsigned short* __restrict__ BT,
                                                 const float* __restrict__ beff,
                                                 void* __restrict__ Yv) {
    __shared__ unsigned short As[128 * 64];   // chunk(r,cc) holds global chunk (r, cc ^ (r&7))
    __shared__ unsigned short Bs[128 * 64];
    int t = threadIdx.x;
    int lane = t & 63, wave = t >> 6;
    int m0 = blockIdx.x * 128, n0 = blockIdx.y * 128;
    const unsigned short* Ab = A + (size_t)m0 * KTOT;
    const unsigned short* Bb = BT + (size_t)n0 * KTOT;

    int srow = lane >> 3;                 // 0..7 within an 8-row staging group
    int sgcc = (lane & 7) ^ srow;         // swizzled global 16B-chunk column

    f32x16 acc[2][2] = {};
    int wr = (wave >> 1) * 64;
    int wc = (wave & 1) * 64;
    int row32 = lane & 31, half = lane >> 5;

    for (int k0 = 0; k0 < KTOT; k0 += 64) {
#pragma unroll
        for (int j = 0; j < 4; j++) {
            int rgrp = wave * 32 + j * 8;   // wave-uniform
            gload_lds16(Ab + ((size_t)(rgrp + srow) * KTOT + k0 + sgcc * 8), As + rgrp * 64);
            gload_lds16(Bb + ((size_t)(rgrp + srow) * KTOT + k0 + sgcc * 8), Bs + rgrp * 64);
        }
        __syncthreads();
#pragma unroll
        for (int ks = 0; ks < 4; ks++) {
            int cidx = ks * 2 + half;       // 16B chunk index (k = cidx*8)
            bf16x8 af[2], bf[2];
#pragma unroll
            for (int mt = 0; mt < 2; mt++) {
                int r = wr + mt * 32 + row32;
                af[mt] = *(const bf16x8*)(As + r * 64 + ((cidx ^ (r & 7)) << 3));
            }
#pragma unroll
            for (int nt = 0; nt < 2; nt++) {
                int c = wc + nt * 32 + row32;
                bf[nt] = *(const bf16x8*)(Bs + c * 64 + ((cidx ^ (c & 7)) << 3));
            }
#pragma unroll
            for (int mt = 0; mt < 2; mt++)
#pragma unroll
                for (int nt = 0; nt < 2; nt++)
                    acc[mt][nt] = __builtin_amdgcn_mfma_f32_32x32x16_bf16(af[mt], bf[nt], acc[mt][nt], 0, 0, 0);
        }
        __syncthreads();
    }
    // epilogue: D layout col=lane&31, row=(reg&3)+8*(reg>>2)+4*half
#pragma unroll
    for (int nt = 0; nt < 2; nt++) {
        int oc = n0 + wc + nt * 32 + row32;
        float bo = beff[oc];
#pragma unroll
        for (int mt = 0; mt < 2; mt++) {
#pragma unroll
            for (int reg = 0; reg < 16; reg++) {
                int rl = (reg & 3) + 8 * (reg >> 2) + 4 * half;
                int mr = m0 + wr + mt * 32 + rl;
                float v = acc[mt][nt][reg] + bo;
                if (BF16OUT) ((unsigned short*)Yv)[(size_t)mr * N + oc] = f2bf(v);
                else         ((float*)Yv)[(size_t)mr * N + oc] = v;
            }
        }
    }
}

// ---------------- LN(1024) + exact GELU, emit bf16 powers [g, g^2, g^3]
__global__ __launch_bounds__(256) void ln_gelu(const unsigned short* __restrict__ y1,
                                               const float* __restrict__ g,
                                               const float* __restrict__ be,
                                               unsigned short* __restrict__ Gpow) {
    __shared__ float red[4];
    int m = blockIdx.x, t = threadIdx.x;
    const unsigned short* row = y1 + (size_t)m * HIDN;
    ushort4 u = *(const ushort4*)(row + 4 * t);
    float v[4] = { bf2f(u.x), bf2f(u.y), bf2f(u.z), bf2f(u.w) };
    float s = v[0] + v[1] + v[2] + v[3];
    for (int off = 32; off > 0; off >>= 1) s += __shfl_down(s, off, 64);
    if ((t & 63) == 0) red[t >> 6] = s;
    __syncthreads();
    float mu = (red[0] + red[1] + red[2] + red[3]) * (1.f / HIDN);
    __syncthreads();
    float ss = 0.f;
#pragma unroll
    for (int j = 0; j < 4; j++) { float d = v[j] - mu; ss += d * d; }
    for (int off = 32; off > 0; off >>= 1) ss += __shfl_down(ss, off, 64);
    if ((t & 63) == 0) red[t >> 6] = ss;
    __syncthreads();
    float rs = rsqrtf((red[0] + red[1] + red[2] + red[3]) * (1.f / HIDN) + 1e-5f);
    float4 gg = *(const float4*)(g + 4 * t);
    float4 bb = *(const float4*)(be + 4 * t);
    float gl[4];
    float gv[4] = { gg.x, gg.y, gg.z, gg.w };
    float bv[4] = { bb.x, bb.y, bb.z, bb.w };
#pragma unroll
    for (int j = 0; j < 4; j++) {
        float xn = (v[j] - mu) * rs * gv[j] + bv[j];
        gl[j] = xn * 0.5f * (1.f + erff(xn * 0.70710678118654752f));
    }
    unsigned short* dst = Gpow + (size_t)m * KTOT + 4 * t;
    ushort4 p1 = { f2bf(gl[0]), f2bf(gl[1]), f2bf(gl[2]), f2bf(gl[3]) };
    ushort4 p2 = { f2bf(gl[0]*gl[0]), f2bf(gl[1]*gl[1]), f2bf(gl[2]*gl[2]), f2bf(gl[3]*gl[3]) };
    ushort4 p3 = { f2bf(gl[0]*gl[0]*gl[0]), f2bf(gl[1]*gl[1]*gl[1]),
                   f2bf(gl[2]*gl[2]*gl[2]), f2bf(gl[3]*gl[3]*gl[3]) };
    *(ushort4*)(dst)          = p1;
    *(ushort4*)(dst + HIDN)   = p2;
    *(ushort4*)(dst + 2*HIDN) = p3;
}

// ---------------- Stage A: LN(512) per row + partial mean over an L-chunk. NO atomics.
// grid (Bsz, LCHUNKS); 4 waves; wave w handles rows w, w+4, ..., w+28.
// lane owns cols {4l..4l+3} and {256+4l..256+4l+3}.
__global__ __launch_bounds__(256) void ln_pool_partial(const float* __restrict__ y2,
                                                       const float* __restrict__ g,
                                                       const float* __restrict__ be,
                                                       float* __restrict__ partial) {
    __shared__ float part[4][OUTN];
    int t = threadIdx.x, lane = t & 63, wave = t >> 6;
    int b = blockIdx.x, chunk = blockIdx.y;
    int mbase = b * LEN + chunk * LROWS;

    float4 gg0 = *(const float4*)(g + 4 * lane);
    float4 gg1 = *(const float4*)(g + 256 + 4 * lane);
    float4 bb0 = *(const float4*)(be + 4 * lane);
    float4 bb1 = *(const float4*)(be + 256 + 4 * lane);

    float acc[8] = {0.f, 0.f, 0.f, 0.f, 0.f, 0.f, 0.f, 0.f};
    for (int rr = wave; rr < LROWS; rr += 4) {
        const float* row = y2 + (size_t)(mbase + rr) * OUTN;
        float4 v0 = *(const float4*)(row + 4 * lane);
        float4 v1 = *(const float4*)(row + 256 + 4 * lane);
        float s  = v0.x + v0.y + v0.z + v0.w + v1.x + v1.y + v1.z + v1.w;
        float ss = v0.x*v0.x + v0.y*v0.y + v0.z*v0.z + v0.w*v0.w
                 + v1.x*v1.x + v1.y*v1.y + v1.z*v1.z + v1.w*v1.w;
        for (int off = 32; off > 0; off >>= 1) {
            s  += __shfl_down(s, off, 64);
            ss += __shfl_down(ss, off, 64);
        }
        s  = __shfl(s, 0, 64);
        ss = __shfl(ss, 0, 64);
        float mu = s * (1.f / OUTN);
        float var = ss * (1.f / OUTN) - mu * mu;
        float rs = rsqrtf(var + 1e-5f);
        acc[0] += (v0.x - mu) * rs * gg0.x + bb0.x;
        acc[1] += (v0.y - mu) * rs * gg0.y + bb0.y;
        acc[2] += (v0.z - mu) * rs * gg0.z + bb0.z;
        acc[3] += (v0.w - mu) * rs * gg0.w + bb0.w;
        acc[4] += (v1.x - mu) * rs * gg1.x + bb1.x;
        acc[5] += (v1.y - mu) * rs * gg1.y + bb1.y;
        acc[6] += (v1.z - mu) * rs * gg1.z + bb1.z;
        acc[7] += (v1.w - mu) * rs * gg1.w + bb1.w;
    }
    // per-wave partials -> LDS
    *(float4*)(&part[wave][4 * lane])       = *(float4*)(&acc[0]);
    *(float4*)(&part[wave][256 + 4 * lane]) = *(float4*)(&acc[4]);
    __syncthreads();
    // 256 threads: thread t sums 4 waves for cols {2t, 2t+1}
    float p0 = part[0][2*t] + part[1][2*t] + part[2][2*t] + part[3][2*t];
    float p1 = part[0][2*t+1] + part[1][2*t+1] + part[2][2*t+1] + part[3][2*t+1];
    float* dst = partial + ((size_t)b * LCHUNKS + chunk) * OUTN;
    *(float2*)(dst + 2 * t) = make_float2(p0, p1);
}

// ---------------- Stage B: reduce 32 chunk-partials -> out[b][o]
__global__ __launch_bounds__(256) void pool_reduce(const float* __restrict__ partial,
                                                   float* __restrict__ out) {
    int b = blockIdx.x, t = threadIdx.x;
    const float* src = partial + (size_t)b * LCHUNKS * OUTN;
    float s0 = 0.f, s1 = 0.f;
    for (int c = 0; c < LCHUNKS; c++) {
        float2 v = *(const float2*)(src + (size_t)c * OUTN + 2 * t);
        s0 += v.x; s1 += v.y;
    }
    *(float2*)(out + (size_t)b * OUTN + 2 * t) = make_float2(s0 * (1.f / LEN), s1 * (1.f / LEN));
}

extern "C" void kernel_launch(void* const* d_in, const int* in_sizes, int n_in,
                              void* d_out, int out_size, void* d_ws, size_t ws_size,
                              hipStream_t stream) {
    const float* x       = (const float*)d_in[0];
    const float* Win     = (const float*)d_in[1];
    const float* bin     = (const float*)d_in[2];
    const float* coeffs1 = (const float*)d_in[3];
    const float* bias1   = (const float*)d_in[4];
    const float* g1      = (const float*)d_in[5];
    const float* beta1   = (const float*)d_in[6];
    const float* coeffs2 = (const float*)d_in[7];
    const float* bias2   = (const float*)d_in[8];
    const float* g2      = (const float*)d_in[9];
    const float* beta2   = (const float*)d_in[10];
    float* out = (float*)d_out;

    char* ws = (char*)d_ws;
    unsigned short* Hpow = (unsigned short*)ws;                         // 100,663,296 B
    char* p1 = ws + (size_t)MTOT * KTOT * 2;
    unsigned short* y1   = (unsigned short*)p1;                         // 33,554,432 B
    float*          y2   = (float*)p1;                                  // alias (same size)
    char* p2 = p1 + (size_t)MTOT * HIDN * 2;
    unsigned short* W1T  = (unsigned short*)p2;                         // 6,291,456 B
    char* p3 = p2 + (size_t)HIDN * KTOT * 2;
    unsigned short* W2T  = (unsigned short*)p3;                         // 3,145,728 B
    char* p4 = p3 + (size_t)OUTN * KTOT * 2;
    float* b1e = (float*)p4;                                            // 4 KB
    float* b2e = (float*)(p4 + HIDN * sizeof(float));                   // 2 KB
    unsigned short* G2pow = Hpow;    // alias: Hpow dead after GEMM1
    float* partial = (float*)W1T;    // alias: W1T dead after GEMM1 (needs 1 MB of 6.3 MB)

    prep_w<<<HIDN, 256, 0, stream>>>(coeffs1, bias1, W1T, b1e);
    prep_w<<<OUTN, 256, 0, stream>>>(coeffs2, bias2, W2T, b2e);
    proj_in<<<MTOT / 16, 256, 0, stream>>>(x, Win, bin, Hpow);
    mfma_gemm<HIDN, true><<<dim3(MTOT / 128, HIDN / 128), 256, 0, stream>>>(Hpow, W1T, b1e, y1);
    ln_gelu<<<MTOT, 256, 0, stream>>>(y1, g1, beta1, G2pow);
    mfma_gemm<OUTN, false><<<dim3(MTOT / 128, OUTN / 128), 256, 0, stream>>>(G2pow, W2T, b2e, y2);
    ln_pool_partial<<<dim3(Bsz, LCHUNKS), 256, 0, stream>>>(y2, g2, beta2, partial);
    pool_reduce<<<Bsz, 256, 0, stream>>>(partial, out);
}

// Round 5
// 314.545 us; speedup vs baseline: 1.5454x; 1.0749x over previous
//
#include <hip/hip_runtime.h>
#include <math.h>

#define Bsz  16
#define CIN  64
#define LEN  1024
#define HIDN 1024
#define OUTN 512
#define MTOT (Bsz*LEN)   // 16384
#define KTOT (3*HIDN)    // 3072
#define LCHUNKS 32
#define LROWS   (LEN/LCHUNKS)  // 32 rows per block

typedef __attribute__((ext_vector_type(8))) short bf16x8;
typedef __attribute__((ext_vector_type(16))) float f32x16;

__device__ __forceinline__ unsigned short f2bf(float x) {
    union { float f; unsigned int u; } v; v.f = x;
    unsigned int r = v.u + 0x7fff + ((v.u >> 16) & 1);   // RNE
    return (unsigned short)(r >> 16);
}
__device__ __forceinline__ float bf2f(unsigned short u) {
    union { unsigned int u; float f; } v; v.u = ((unsigned int)u) << 16;
    return v.f;
}
__device__ __forceinline__ void gload_lds16(const void* g, void* l) {
    // width=16 async global->LDS; LDS dest = wave-uniform base + lane*16
    __builtin_amdgcn_global_load_lds((const __attribute__((address_space(1))) void*)g,
                                     (__attribute__((address_space(3))) void*)l, 16, 0, 0);
}

// ---------------- prep_all: one launch doing
//  [0,1024)      coeffs1 row -> W1T bf16 + b1e
//  [1024,1536)   coeffs2 row -> W2T bf16 + b2e
//  [1536,1792)   x (B,C,L) 64x64 tile transpose -> xT[b][l][c] bf16
//  [1792,1808)   Win (C,H) 64x64 tile transpose -> WinT[h][c] bf16
__global__ __launch_bounds__(256) void prep_all(const float* __restrict__ coeffs1,
                                                const float* __restrict__ bias1,
                                                const float* __restrict__ coeffs2,
                                                const float* __restrict__ bias2,
                                                const float* __restrict__ x,
                                                const float* __restrict__ Win,
                                                unsigned short* __restrict__ W1T,
                                                float* __restrict__ b1e,
                                                unsigned short* __restrict__ W2T,
                                                float* __restrict__ b2e,
                                                unsigned short* __restrict__ xT,
                                                unsigned short* __restrict__ WinT) {
    __shared__ float sm[64 * 65];
    int bid = blockIdx.x, t = threadIdx.x;
    if (bid < 1536) {
        const float* coeffs; const float* bias; unsigned short* WT; float* beff; int o;
        if (bid < 1024) { coeffs = coeffs1; bias = bias1; WT = W1T; beff = b1e; o = bid; }
        else            { coeffs = coeffs2; bias = bias2; WT = W2T; beff = b2e; o = bid - 1024; }
        float s = 0.f;
        unsigned short* wrow = WT + (size_t)o * KTOT;
        for (int c = t; c < HIDN; c += 256) {
            float4 v = *(const float4*)(coeffs + ((size_t)o * HIDN + c) * 4);
            s += v.x;
            wrow[c]            = f2bf(v.y);
            wrow[HIDN + c]     = f2bf(v.z);
            wrow[2 * HIDN + c] = f2bf(v.w);
        }
        for (int off = 32; off > 0; off >>= 1) s += __shfl_down(s, off, 64);
        if ((t & 63) == 0) sm[t >> 6] = s;
        __syncthreads();
        if (t == 0) beff[o] = bias[o] + sm[0] + sm[1] + sm[2] + sm[3];
    } else {
        // 64x64 fp32 -> bf16 transposed tile
        const float* src; unsigned short* dstbase; size_t src_rstride;
        int c0;  // column offset in source row
        if (bid < 1792) {
            int tile = bid - 1536; int b = tile >> 4; c0 = (tile & 15) * 64;
            src = x + (size_t)b * CIN * LEN;  src_rstride = LEN;
            dstbase = xT + ((size_t)b * LEN + c0) * CIN;
        } else {
            int tile = bid - 1792; c0 = tile * 64;
            src = Win; src_rstride = HIDN;
            dstbase = WinT + (size_t)c0 * CIN;
        }
#pragma unroll
        for (int it = 0; it < 4; it++) {
            int idx = t + it * 256;
            int c = idx >> 4, q = idx & 15;
            float4 v = *(const float4*)(src + (size_t)c * src_rstride + c0 + q * 4);
            sm[c * 65 + q * 4 + 0] = v.x;
            sm[c * 65 + q * 4 + 1] = v.y;
            sm[c * 65 + q * 4 + 2] = v.z;
            sm[c * 65 + q * 4 + 3] = v.w;
        }
        __syncthreads();
        int ll = t >> 2, cg = (t & 3) * 16;
        unsigned short* dst = dstbase + (size_t)ll * CIN + cg;
#pragma unroll
        for (int j = 0; j < 4; j++) {
            int c = cg + j * 4;
            ushort4 w = { f2bf(sm[(c + 0) * 65 + ll]), f2bf(sm[(c + 1) * 65 + ll]),
                          f2bf(sm[(c + 2) * 65 + ll]), f2bf(sm[(c + 3) * 65 + ll]) };
            *(ushort4*)(dst + j * 4) = w;
        }
    }
}

// ---------------- proj_mfma: Hpow planes = powers of (xT @ WinT^T + bin)
// Same 128x128 tile structure as mfma_gemm but K=64 (single staging round).
__global__ __launch_bounds__(256) void proj_mfma(const unsigned short* __restrict__ xT,
                                                 const unsigned short* __restrict__ WinT,
                                                 const float* __restrict__ bin,
                                                 unsigned short* __restrict__ Hpow) {
    __shared__ unsigned short As[128 * 64];
    __shared__ unsigned short Bs[128 * 64];
    int t = threadIdx.x, lane = t & 63, wave = t >> 6;
    int m0 = blockIdx.x * 128, n0 = blockIdx.y * 128;
    int srow = lane >> 3, sgcc = (lane & 7) ^ srow;
    const unsigned short* Ab = xT + (size_t)m0 * CIN;
    const unsigned short* Bb = WinT + (size_t)n0 * CIN;

    f32x16 acc[2][2] = {};
    int wr = (wave >> 1) * 64, wc = (wave & 1) * 64;
    int row32 = lane & 31, half = lane >> 5;

#pragma unroll
    for (int j = 0; j < 4; j++) {
        int rgrp = wave * 32 + j * 8;
        gload_lds16(Ab + (size_t)(rgrp + srow) * CIN + sgcc * 8, As + rgrp * 64);
        gload_lds16(Bb + (size_t)(rgrp + srow) * CIN + sgcc * 8, Bs + rgrp * 64);
    }
    __syncthreads();
#pragma unroll
    for (int ks = 0; ks < 4; ks++) {
        int cidx = ks * 2 + half;
        bf16x8 af[2], bf[2];
#pragma unroll
        for (int mt = 0; mt < 2; mt++) {
            int r = wr + mt * 32 + row32;
            af[mt] = *(const bf16x8*)(As + r * 64 + ((cidx ^ (r & 7)) << 3));
        }
#pragma unroll
        for (int nt = 0; nt < 2; nt++) {
            int c = wc + nt * 32 + row32;
            bf[nt] = *(const bf16x8*)(Bs + c * 64 + ((cidx ^ (c & 7)) << 3));
        }
#pragma unroll
        for (int mt = 0; mt < 2; mt++)
#pragma unroll
            for (int nt = 0; nt < 2; nt++)
                acc[mt][nt] = __builtin_amdgcn_mfma_f32_32x32x16_bf16(af[mt], bf[nt], acc[mt][nt], 0, 0, 0);
    }
    // epilogue: h = acc + bin; write [h, h^2, h^3] planes
#pragma unroll
    for (int nt = 0; nt < 2; nt++) {
        int oc = n0 + wc + nt * 32 + row32;
        float bo = bin[oc];
#pragma unroll
        for (int mt = 0; mt < 2; mt++) {
#pragma unroll
            for (int reg = 0; reg < 16; reg++) {
                int rl = (reg & 3) + 8 * (reg >> 2) + 4 * half;
                size_t mr = (size_t)(m0 + wr + mt * 32 + rl);
                float h = acc[mt][nt][reg] + bo;
                unsigned short* d = Hpow + mr * KTOT + oc;
                d[0]        = f2bf(h);
                d[HIDN]     = f2bf(h * h);
                d[2 * HIDN] = f2bf(h * h * h);
            }
        }
    }
}

// ---------------- MFMA GEMM (32x32x16): Y[M][N] = A(M x 3072) @ BT(N x 3072)^T + beff
template<int N, bool BF16OUT>
__global__ __launch_bounds__(256) void mfma_gemm(const unsigned short* __restrict__ A,
                                                 const unsigned short* __restrict__ BT,
                                                 const float* __restrict__ beff,
                                                 void* __restrict__ Yv) {
    __shared__ unsigned short As[128 * 64];
    __shared__ unsigned short Bs[128 * 64];
    int t = threadIdx.x;
    int lane = t & 63, wave = t >> 6;
    int m0 = blockIdx.x * 128, n0 = blockIdx.y * 128;
    const unsigned short* Ab = A + (size_t)m0 * KTOT;
    const unsigned short* Bb = BT + (size_t)n0 * KTOT;

    int srow = lane >> 3;
    int sgcc = (lane & 7) ^ srow;

    f32x16 acc[2][2] = {};
    int wr = (wave >> 1) * 64;
    int wc = (wave & 1) * 64;
    int row32 = lane & 31, half = lane >> 5;

    for (int k0 = 0; k0 < KTOT; k0 += 64) {
#pragma unroll
        for (int j = 0; j < 4; j++) {
            int rgrp = wave * 32 + j * 8;
            gload_lds16(Ab + ((size_t)(rgrp + srow) * KTOT + k0 + sgcc * 8), As + rgrp * 64);
            gload_lds16(Bb + ((size_t)(rgrp + srow) * KTOT + k0 + sgcc * 8), Bs + rgrp * 64);
        }
        __syncthreads();
#pragma unroll
        for (int ks = 0; ks < 4; ks++) {
            int cidx = ks * 2 + half;
            bf16x8 af[2], bf[2];
#pragma unroll
            for (int mt = 0; mt < 2; mt++) {
                int r = wr + mt * 32 + row32;
                af[mt] = *(const bf16x8*)(As + r * 64 + ((cidx ^ (r & 7)) << 3));
            }
#pragma unroll
            for (int nt = 0; nt < 2; nt++) {
                int c = wc + nt * 32 + row32;
                bf[nt] = *(const bf16x8*)(Bs + c * 64 + ((cidx ^ (c & 7)) << 3));
            }
#pragma unroll
            for (int mt = 0; mt < 2; mt++)
#pragma unroll
                for (int nt = 0; nt < 2; nt++)
                    acc[mt][nt] = __builtin_amdgcn_mfma_f32_32x32x16_bf16(af[mt], bf[nt], acc[mt][nt], 0, 0, 0);
        }
        __syncthreads();
    }
#pragma unroll
    for (int nt = 0; nt < 2; nt++) {
        int oc = n0 + wc + nt * 32 + row32;
        float bo = beff[oc];
#pragma unroll
        for (int mt = 0; mt < 2; mt++) {
#pragma unroll
            for (int reg = 0; reg < 16; reg++) {
                int rl = (reg & 3) + 8 * (reg >> 2) + 4 * half;
                int mr = m0 + wr + mt * 32 + rl;
                float v = acc[mt][nt][reg] + bo;
                if (BF16OUT) ((unsigned short*)Yv)[(size_t)mr * N + oc] = f2bf(v);
                else         ((float*)Yv)[(size_t)mr * N + oc] = v;
            }
        }
    }
}

// ---------------- LN(1024) + exact GELU, emit bf16 powers [g, g^2, g^3]
__global__ __launch_bounds__(256) void ln_gelu(const unsigned short* __restrict__ y1,
                                               const float* __restrict__ g,
                                               const float* __restrict__ be,
                                               unsigned short* __restrict__ Gpow) {
    __shared__ float red[4];
    int m = blockIdx.x, t = threadIdx.x;
    const unsigned short* row = y1 + (size_t)m * HIDN;
    ushort4 u = *(const ushort4*)(row + 4 * t);
    float v[4] = { bf2f(u.x), bf2f(u.y), bf2f(u.z), bf2f(u.w) };
    float s = v[0] + v[1] + v[2] + v[3];
    for (int off = 32; off > 0; off >>= 1) s += __shfl_down(s, off, 64);
    if ((t & 63) == 0) red[t >> 6] = s;
    __syncthreads();
    float mu = (red[0] + red[1] + red[2] + red[3]) * (1.f / HIDN);
    __syncthreads();
    float ss = 0.f;
#pragma unroll
    for (int j = 0; j < 4; j++) { float d = v[j] - mu; ss += d * d; }
    for (int off = 32; off > 0; off >>= 1) ss += __shfl_down(ss, off, 64);
    if ((t & 63) == 0) red[t >> 6] = ss;
    __syncthreads();
    float rs = rsqrtf((red[0] + red[1] + red[2] + red[3]) * (1.f / HIDN) + 1e-5f);
    float4 gg = *(const float4*)(g + 4 * t);
    float4 bb = *(const float4*)(be + 4 * t);
    float gl[4];
    float gv[4] = { gg.x, gg.y, gg.z, gg.w };
    float bv[4] = { bb.x, bb.y, bb.z, bb.w };
#pragma unroll
    for (int j = 0; j < 4; j++) {
        float xn = (v[j] - mu) * rs * gv[j] + bv[j];
        gl[j] = xn * 0.5f * (1.f + erff(xn * 0.70710678118654752f));
    }
    unsigned short* dst = Gpow + (size_t)m * KTOT + 4 * t;
    ushort4 p1 = { f2bf(gl[0]), f2bf(gl[1]), f2bf(gl[2]), f2bf(gl[3]) };
    ushort4 p2 = { f2bf(gl[0]*gl[0]), f2bf(gl[1]*gl[1]), f2bf(gl[2]*gl[2]), f2bf(gl[3]*gl[3]) };
    ushort4 p3 = { f2bf(gl[0]*gl[0]*gl[0]), f2bf(gl[1]*gl[1]*gl[1]),
                   f2bf(gl[2]*gl[2]*gl[2]), f2bf(gl[3]*gl[3]*gl[3]) };
    *(ushort4*)(dst)          = p1;
    *(ushort4*)(dst + HIDN)   = p2;
    *(ushort4*)(dst + 2*HIDN) = p3;
}

// ---------------- Stage A: LN(512) per row + partial mean over an L-chunk. NO atomics.
__global__ __launch_bounds__(256) void ln_pool_partial(const float* __restrict__ y2,
                                                       const float* __restrict__ g,
                                                       const float* __restrict__ be,
                                                       float* __restrict__ partial) {
    __shared__ float part[4][OUTN];
    int t = threadIdx.x, lane = t & 63, wave = t >> 6;
    int b = blockIdx.x, chunk = blockIdx.y;
    int mbase = b * LEN + chunk * LROWS;

    float4 gg0 = *(const float4*)(g + 4 * lane);
    float4 gg1 = *(const float4*)(g + 256 + 4 * lane);
    float4 bb0 = *(const float4*)(be + 4 * lane);
    float4 bb1 = *(const float4*)(be + 256 + 4 * lane);

    float acc[8] = {0.f, 0.f, 0.f, 0.f, 0.f, 0.f, 0.f, 0.f};
    for (int rr = wave; rr < LROWS; rr += 4) {
        const float* row = y2 + (size_t)(mbase + rr) * OUTN;
        float4 v0 = *(const float4*)(row + 4 * lane);
        float4 v1 = *(const float4*)(row + 256 + 4 * lane);
        float s  = v0.x + v0.y + v0.z + v0.w + v1.x + v1.y + v1.z + v1.w;
        float ss = v0.x*v0.x + v0.y*v0.y + v0.z*v0.z + v0.w*v0.w
                 + v1.x*v1.x + v1.y*v1.y + v1.z*v1.z + v1.w*v1.w;
        for (int off = 32; off > 0; off >>= 1) {
            s  += __shfl_down(s, off, 64);
            ss += __shfl_down(ss, off, 64);
        }
        s  = __shfl(s, 0, 64);
        ss = __shfl(ss, 0, 64);
        float mu = s * (1.f / OUTN);
        float var = ss * (1.f / OUTN) - mu * mu;
        float rs = rsqrtf(var + 1e-5f);
        acc[0] += (v0.x - mu) * rs * gg0.x + bb0.x;
        acc[1] += (v0.y - mu) * rs * gg0.y + bb0.y;
        acc[2] += (v0.z - mu) * rs * gg0.z + bb0.z;
        acc[3] += (v0.w - mu) * rs * gg0.w + bb0.w;
        acc[4] += (v1.x - mu) * rs * gg1.x + bb1.x;
        acc[5] += (v1.y - mu) * rs * gg1.y + bb1.y;
        acc[6] += (v1.z - mu) * rs * gg1.z + bb1.z;
        acc[7] += (v1.w - mu) * rs * gg1.w + bb1.w;
    }
    *(float4*)(&part[wave][4 * lane])       = *(float4*)(&acc[0]);
    *(float4*)(&part[wave][256 + 4 * lane]) = *(float4*)(&acc[4]);
    __syncthreads();
    float p0 = part[0][2*t] + part[1][2*t] + part[2][2*t] + part[3][2*t];
    float p1 = part[0][2*t+1] + part[1][2*t+1] + part[2][2*t+1] + part[3][2*t+1];
    float* dst = partial + ((size_t)b * LCHUNKS + chunk) * OUTN;
    *(float2*)(dst + 2 * t) = make_float2(p0, p1);
}

// ---------------- Stage B: reduce 32 chunk-partials -> out[b][o]
__global__ __launch_bounds__(256) void pool_reduce(const float* __restrict__ partial,
                                                   float* __restrict__ out) {
    int b = blockIdx.x, t = threadIdx.x;
    const float* src = partial + (size_t)b * LCHUNKS * OUTN;
    float s0 = 0.f, s1 = 0.f;
    for (int c = 0; c < LCHUNKS; c++) {
        float2 v = *(const float2*)(src + (size_t)c * OUTN + 2 * t);
        s0 += v.x; s1 += v.y;
    }
    *(float2*)(out + (size_t)b * OUTN + 2 * t) = make_float2(s0 * (1.f / LEN), s1 * (1.f / LEN));
}

extern "C" void kernel_launch(void* const* d_in, const int* in_sizes, int n_in,
                              void* d_out, int out_size, void* d_ws, size_t ws_size,
                              hipStream_t stream) {
    const float* x       = (const float*)d_in[0];
    const float* Win     = (const float*)d_in[1];
    const float* bin     = (const float*)d_in[2];
    const float* coeffs1 = (const float*)d_in[3];
    const float* bias1   = (const float*)d_in[4];
    const float* g1      = (const float*)d_in[5];
    const float* beta1   = (const float*)d_in[6];
    const float* coeffs2 = (const float*)d_in[7];
    const float* bias2   = (const float*)d_in[8];
    const float* g2      = (const float*)d_in[9];
    const float* beta2   = (const float*)d_in[10];
    float* out = (float*)d_out;

    char* ws = (char*)d_ws;
    unsigned short* Hpow = (unsigned short*)ws;                         // 100,663,296 B
    char* p1 = ws + (size_t)MTOT * KTOT * 2;
    unsigned short* y1   = (unsigned short*)p1;                         // 33,554,432 B
    float*          y2   = (float*)p1;                                  // alias (same size)
    char* p2 = p1 + (size_t)MTOT * HIDN * 2;
    unsigned short* W1T  = (unsigned short*)p2;                         // 6,291,456 B
    char* p3 = p2 + (size_t)HIDN * KTOT * 2;
    unsigned short* W2T  = (unsigned short*)p3;                         // 3,145,728 B
    char* p4 = p3 + (size_t)OUTN * KTOT * 2;
    float* b1e = (float*)p4;                                            // 4 KB
    float* b2e = (float*)(p4 + HIDN * sizeof(float));                   // 2 KB
    char* p5 = p4 + (HIDN + OUTN) * sizeof(float);
    unsigned short* xT   = (unsigned short*)p5;                         // 2,097,152 B
    char* p6 = p5 + (size_t)MTOT * CIN * 2;
    unsigned short* WinT = (unsigned short*)p6;                         // 131,072 B
    unsigned short* G2pow = Hpow;    // alias: Hpow dead after GEMM1
    float* partial = (float*)W1T;    // alias: W1T dead after GEMM1 (needs 1 MB)

    prep_all<<<1808, 256, 0, stream>>>(coeffs1, bias1, coeffs2, bias2, x, Win,
                                       W1T, b1e, W2T, b2e, xT, WinT);
    proj_mfma<<<dim3(MTOT / 128, HIDN / 128), 256, 0, stream>>>(xT, WinT, bin, Hpow);
    mfma_gemm<HIDN, true><<<dim3(MTOT / 128, HIDN / 128), 256, 0, stream>>>(Hpow, W1T, b1e, y1);
    ln_gelu<<<MTOT, 256, 0, stream>>>(y1, g1, beta1, G2pow);
    mfma_gemm<OUTN, false><<<dim3(MTOT / 128, OUTN / 128), 256, 0, stream>>>(G2pow, W2T, b2e, y2);
    ln_pool_partial<<<dim3(Bsz, LCHUNKS), 256, 0, stream>>>(y2, g2, beta2, partial);
    pool_reduce<<<Bsz, 256, 0, stream>>>(partial, out);
}

// Round 6
// 313.246 us; speedup vs baseline: 1.5518x; 1.0041x over previous
//
#include <hip/hip_runtime.h>
#include <math.h>

#define Bsz  16
#define CIN  64
#define LEN  1024
#define HIDN 1024
#define OUTN 512
#define MTOT (Bsz*LEN)   // 16384
#define KTOT (3*HIDN)    // 3072
#define LCHUNKS 32
#define LROWS   (LEN/LCHUNKS)  // 32 rows per block

typedef __attribute__((ext_vector_type(8))) short bf16x8;
typedef __attribute__((ext_vector_type(16))) float f32x16;

__device__ __forceinline__ unsigned short f2bf(float x) {
    union { float f; unsigned int u; } v; v.f = x;
    unsigned int r = v.u + 0x7fff + ((v.u >> 16) & 1);   // RNE
    return (unsigned short)(r >> 16);
}
__device__ __forceinline__ float bf2f(unsigned short u) {
    union { unsigned int u; float f; } v; v.u = ((unsigned int)u) << 16;
    return v.f;
}
__device__ __forceinline__ void gload_lds16(const void* g, void* l) {
    __builtin_amdgcn_global_load_lds((const __attribute__((address_space(1))) void*)g,
                                     (__attribute__((address_space(3))) void*)l, 16, 0, 0);
}

// ---------------- prep_all: coeffs->WT bf16 + beff; x,Win 64x64 transposes -> bf16
__global__ __launch_bounds__(256) void prep_all(const float* __restrict__ coeffs1,
                                                const float* __restrict__ bias1,
                                                const float* __restrict__ coeffs2,
                                                const float* __restrict__ bias2,
                                                const float* __restrict__ x,
                                                const float* __restrict__ Win,
                                                unsigned short* __restrict__ W1T,
                                                float* __restrict__ b1e,
                                                unsigned short* __restrict__ W2T,
                                                float* __restrict__ b2e,
                                                unsigned short* __restrict__ xT,
                                                unsigned short* __restrict__ WinT) {
    __shared__ float sm[64 * 65];
    int bid = blockIdx.x, t = threadIdx.x;
    if (bid < 1536) {
        const float* coeffs; const float* bias; unsigned short* WT; float* beff; int o;
        if (bid < 1024) { coeffs = coeffs1; bias = bias1; WT = W1T; beff = b1e; o = bid; }
        else            { coeffs = coeffs2; bias = bias2; WT = W2T; beff = b2e; o = bid - 1024; }
        float s = 0.f;
        unsigned short* wrow = WT + (size_t)o * KTOT;
        for (int c = t; c < HIDN; c += 256) {
            float4 v = *(const float4*)(coeffs + ((size_t)o * HIDN + c) * 4);
            s += v.x;
            wrow[c]            = f2bf(v.y);
            wrow[HIDN + c]     = f2bf(v.z);
            wrow[2 * HIDN + c] = f2bf(v.w);
        }
        for (int off = 32; off > 0; off >>= 1) s += __shfl_down(s, off, 64);
        if ((t & 63) == 0) sm[t >> 6] = s;
        __syncthreads();
        if (t == 0) beff[o] = bias[o] + sm[0] + sm[1] + sm[2] + sm[3];
    } else {
        const float* src; unsigned short* dstbase; size_t src_rstride;
        int c0;
        if (bid < 1792) {
            int tile = bid - 1536; int b = tile >> 4; c0 = (tile & 15) * 64;
            src = x + (size_t)b * CIN * LEN;  src_rstride = LEN;
            dstbase = xT + ((size_t)b * LEN + c0) * CIN;
        } else {
            int tile = bid - 1792; c0 = tile * 64;
            src = Win; src_rstride = HIDN;
            dstbase = WinT + (size_t)c0 * CIN;
        }
#pragma unroll
        for (int it = 0; it < 4; it++) {
            int idx = t + it * 256;
            int c = idx >> 4, q = idx & 15;
            float4 v = *(const float4*)(src + (size_t)c * src_rstride + c0 + q * 4);
            sm[c * 65 + q * 4 + 0] = v.x;
            sm[c * 65 + q * 4 + 1] = v.y;
            sm[c * 65 + q * 4 + 2] = v.z;
            sm[c * 65 + q * 4 + 3] = v.w;
        }
        __syncthreads();
        int ll = t >> 2, cg = (t & 3) * 16;
        unsigned short* dst = dstbase + (size_t)ll * CIN + cg;
#pragma unroll
        for (int j = 0; j < 4; j++) {
            int c = cg + j * 4;
            ushort4 w = { f2bf(sm[(c + 0) * 65 + ll]), f2bf(sm[(c + 1) * 65 + ll]),
                          f2bf(sm[(c + 2) * 65 + ll]), f2bf(sm[(c + 3) * 65 + ll]) };
            *(ushort4*)(dst + j * 4) = w;
        }
    }
}

// ---------------- proj_mfma: Hpow planes = powers of (xT @ WinT^T + bin)
// K=64 single staging round; epilogue transposes through LDS for 16B stores.
__global__ __launch_bounds__(256) void proj_mfma(const unsigned short* __restrict__ xT,
                                                 const unsigned short* __restrict__ WinT,
                                                 const float* __restrict__ bin,
                                                 unsigned short* __restrict__ Hpow) {
    __shared__ unsigned short smem[2 * 128 * 64];   // staging; reused as 128x128 ht
    unsigned short* As = smem;
    unsigned short* Bs = smem + 128 * 64;
    unsigned short* ht = smem;                      // 128*128 after K-loop
    int t = threadIdx.x, lane = t & 63, wave = t >> 6;
    int m0 = blockIdx.x * 128, n0 = blockIdx.y * 128;
    int srow = lane >> 3, sgcc = (lane & 7) ^ srow;
    const unsigned short* Ab = xT + (size_t)m0 * CIN;
    const unsigned short* Bb = WinT + (size_t)n0 * CIN;

    f32x16 acc[2][2] = {};
    int wr = (wave >> 1) * 64, wc = (wave & 1) * 64;
    int row32 = lane & 31, half = lane >> 5;

#pragma unroll
    for (int j = 0; j < 4; j++) {
        int rgrp = wave * 32 + j * 8;
        gload_lds16(Ab + (size_t)(rgrp + srow) * CIN + sgcc * 8, As + rgrp * 64);
        gload_lds16(Bb + (size_t)(rgrp + srow) * CIN + sgcc * 8, Bs + rgrp * 64);
    }
    __syncthreads();
#pragma unroll
    for (int ks = 0; ks < 4; ks++) {
        int cidx = ks * 2 + half;
        bf16x8 af[2], bf[2];
#pragma unroll
        for (int mt = 0; mt < 2; mt++) {
            int r = wr + mt * 32 + row32;
            af[mt] = *(const bf16x8*)(As + r * 64 + ((cidx ^ (r & 7)) << 3));
        }
#pragma unroll
        for (int nt = 0; nt < 2; nt++) {
            int c = wc + nt * 32 + row32;
            bf[nt] = *(const bf16x8*)(Bs + c * 64 + ((cidx ^ (c & 7)) << 3));
        }
#pragma unroll
        for (int mt = 0; mt < 2; mt++)
#pragma unroll
            for (int nt = 0; nt < 2; nt++)
                acc[mt][nt] = __builtin_amdgcn_mfma_f32_32x32x16_bf16(af[mt], bf[nt], acc[mt][nt], 0, 0, 0);
    }
    __syncthreads();   // all ds_reads done; safe to reuse smem as ht
    // h (+bias) -> LDS in row-major bf16
#pragma unroll
    for (int nt = 0; nt < 2; nt++) {
        int ocl = wc + nt * 32 + row32;
        float bo = bin[n0 + ocl];
#pragma unroll
        for (int mt = 0; mt < 2; mt++) {
#pragma unroll
            for (int reg = 0; reg < 16; reg++) {
                int rl = wr + mt * 32 + (reg & 3) + 8 * (reg >> 2) + 4 * half;
                ht[rl * 128 + ocl] = f2bf(acc[mt][nt][reg] + bo);
            }
        }
    }
    __syncthreads();
    // 16B-vector power writes: 8 passes, 16 lanes per row (256B contiguous/row)
#pragma unroll
    for (int p = 0; p < 8; p++) {
        int r = p * 16 + (t >> 4);
        int c = (t & 15) * 8;
        bf16x8 hv = *(const bf16x8*)(ht + r * 128 + c);
        bf16x8 h2v, h3v;
#pragma unroll
        for (int j = 0; j < 8; j++) {
            float f = bf2f((unsigned short)hv[j]);
            float f2 = f * f;
            h2v[j] = (short)f2bf(f2);
            h3v[j] = (short)f2bf(f2 * f);
        }
        unsigned short* d = Hpow + (size_t)(m0 + r) * KTOT + n0 + c;
        *(bf16x8*)(d)            = hv;
        *(bf16x8*)(d + HIDN)     = h2v;
        *(bf16x8*)(d + 2 * HIDN) = h3v;
    }
}

// ---------------- MFMA GEMM (32x32x16): Y[M][N] = A(M x 3072) @ BT(N x 3072)^T + beff
template<int N, bool BF16OUT>
__global__ __launch_bounds__(256) void mfma_gemm(const unsigned short* __restrict__ A,
                                                 const unsigned short* __restrict__ BT,
                                                 const float* __restrict__ beff,
                                                 void* __restrict__ Yv) {
    __shared__ unsigned short As[128 * 64];
    __shared__ unsigned short Bs[128 * 64];
    int t = threadIdx.x;
    int lane = t & 63, wave = t >> 6;
    int m0 = blockIdx.x * 128, n0 = blockIdx.y * 128;
    const unsigned short* Ab = A + (size_t)m0 * KTOT;
    const unsigned short* Bb = BT + (size_t)n0 * KTOT;

    int srow = lane >> 3;
    int sgcc = (lane & 7) ^ srow;

    f32x16 acc[2][2] = {};
    int wr = (wave >> 1) * 64;
    int wc = (wave & 1) * 64;
    int row32 = lane & 31, half = lane >> 5;

    for (int k0 = 0; k0 < KTOT; k0 += 64) {
#pragma unroll
        for (int j = 0; j < 4; j++) {
            int rgrp = wave * 32 + j * 8;
            gload_lds16(Ab + ((size_t)(rgrp + srow) * KTOT + k0 + sgcc * 8), As + rgrp * 64);
            gload_lds16(Bb + ((size_t)(rgrp + srow) * KTOT + k0 + sgcc * 8), Bs + rgrp * 64);
        }
        __syncthreads();
#pragma unroll
        for (int ks = 0; ks < 4; ks++) {
            int cidx = ks * 2 + half;
            bf16x8 af[2], bf[2];
#pragma unroll
            for (int mt = 0; mt < 2; mt++) {
                int r = wr + mt * 32 + row32;
                af[mt] = *(const bf16x8*)(As + r * 64 + ((cidx ^ (r & 7)) << 3));
            }
#pragma unroll
            for (int nt = 0; nt < 2; nt++) {
                int c = wc + nt * 32 + row32;
                bf[nt] = *(const bf16x8*)(Bs + c * 64 + ((cidx ^ (c & 7)) << 3));
            }
#pragma unroll
            for (int mt = 0; mt < 2; mt++)
#pragma unroll
                for (int nt = 0; nt < 2; nt++)
                    acc[mt][nt] = __builtin_amdgcn_mfma_f32_32x32x16_bf16(af[mt], bf[nt], acc[mt][nt], 0, 0, 0);
        }
        __syncthreads();
    }
#pragma unroll
    for (int nt = 0; nt < 2; nt++) {
        int oc = n0 + wc + nt * 32 + row32;
        float bo = beff[oc];
#pragma unroll
        for (int mt = 0; mt < 2; mt++) {
#pragma unroll
            for (int reg = 0; reg < 16; reg++) {
                int rl = (reg & 3) + 8 * (reg >> 2) + 4 * half;
                int mr = m0 + wr + mt * 32 + rl;
                float v = acc[mt][nt][reg] + bo;
                if (BF16OUT) ((unsigned short*)Yv)[(size_t)mr * N + oc] = f2bf(v);
                else         ((float*)Yv)[(size_t)mr * N + oc] = v;
            }
        }
    }
}

// ---------------- LN(1024) + exact GELU, emit bf16 powers; 2 rows/block, 16B ld/st
__global__ __launch_bounds__(256) void ln_gelu(const unsigned short* __restrict__ y1,
                                               const float* __restrict__ g,
                                               const float* __restrict__ be,
                                               unsigned short* __restrict__ Gpow) {
    __shared__ float2 red[2][2];   // [row-in-block][wave-in-row]
    int t = threadIdx.x;
    int rhalf = t >> 7, l = t & 127, wid = (t >> 6) & 1;
    int m = blockIdx.x * 2 + rhalf;
    bf16x8 u = *(const bf16x8*)(y1 + (size_t)m * HIDN + l * 8);
    float v[8];
    float s = 0.f, ss = 0.f;
#pragma unroll
    for (int j = 0; j < 8; j++) {
        v[j] = bf2f((unsigned short)u[j]);
        s += v[j]; ss += v[j] * v[j];
    }
    for (int off = 32; off > 0; off >>= 1) {
        s  += __shfl_down(s, off, 64);
        ss += __shfl_down(ss, off, 64);
    }
    if ((t & 63) == 0) red[rhalf][wid] = make_float2(s, ss);
    __syncthreads();
    float sT  = red[rhalf][0].x + red[rhalf][1].x;
    float ssT = red[rhalf][0].y + red[rhalf][1].y;
    float mu = sT * (1.f / HIDN);
    float var = ssT * (1.f / HIDN) - mu * mu;
    float rs = rsqrtf(var + 1e-5f);
    float4 gA = *(const float4*)(g + l * 8),  gB = *(const float4*)(g + l * 8 + 4);
    float4 bA = *(const float4*)(be + l * 8), bB = *(const float4*)(be + l * 8 + 4);
    float gv[8] = { gA.x, gA.y, gA.z, gA.w, gB.x, gB.y, gB.z, gB.w };
    float bv[8] = { bA.x, bA.y, bA.z, bA.w, bB.x, bB.y, bB.z, bB.w };
    bf16x8 p1, p2, p3;
#pragma unroll
    for (int j = 0; j < 8; j++) {
        float xn = (v[j] - mu) * rs * gv[j] + bv[j];
        float gl = xn * 0.5f * (1.f + erff(xn * 0.70710678118654752f));
        float g2 = gl * gl;
        p1[j] = (short)f2bf(gl);
        p2[j] = (short)f2bf(g2);
        p3[j] = (short)f2bf(g2 * gl);
    }
    unsigned short* dst = Gpow + (size_t)m * KTOT + l * 8;
    *(bf16x8*)(dst)            = p1;
    *(bf16x8*)(dst + HIDN)     = p2;
    *(bf16x8*)(dst + 2 * HIDN) = p3;
}

// ---------------- Stage A: LN(512) per row (bf16 y2) + partial mean over L-chunk
__global__ __launch_bounds__(256) void ln_pool_partial(const unsigned short* __restrict__ y2,
                                                       const float* __restrict__ g,
                                                       const float* __restrict__ be,
                                                       float* __restrict__ partial) {
    __shared__ float part[4][OUTN];
    int t = threadIdx.x, lane = t & 63, wave = t >> 6;
    int b = blockIdx.x, chunk = blockIdx.y;
    int mbase = b * LEN + chunk * LROWS;

    float4 gA = *(const float4*)(g + 8 * lane),  gB = *(const float4*)(g + 8 * lane + 4);
    float4 bA = *(const float4*)(be + 8 * lane), bB = *(const float4*)(be + 8 * lane + 4);
    float gv[8] = { gA.x, gA.y, gA.z, gA.w, gB.x, gB.y, gB.z, gB.w };
    float bv[8] = { bA.x, bA.y, bA.z, bA.w, bB.x, bB.y, bB.z, bB.w };

    float acc[8] = {0.f, 0.f, 0.f, 0.f, 0.f, 0.f, 0.f, 0.f};
    for (int rr = wave; rr < LROWS; rr += 4) {
        bf16x8 u = *(const bf16x8*)(y2 + (size_t)(mbase + rr) * OUTN + 8 * lane);
        float v[8];
        float s = 0.f, ss = 0.f;
#pragma unroll
        for (int j = 0; j < 8; j++) {
            v[j] = bf2f((unsigned short)u[j]);
            s += v[j]; ss += v[j] * v[j];
        }
        for (int off = 32; off > 0; off >>= 1) {
            s  += __shfl_down(s, off, 64);
            ss += __shfl_down(ss, off, 64);
        }
        s  = __shfl(s, 0, 64);
        ss = __shfl(ss, 0, 64);
        float mu = s * (1.f / OUTN);
        float var = ss * (1.f / OUTN) - mu * mu;
        float rs = rsqrtf(var + 1e-5f);
#pragma unroll
        for (int j = 0; j < 8; j++)
            acc[j] += (v[j] - mu) * rs * gv[j] + bv[j];
    }
    *(float4*)(&part[wave][8 * lane])     = *(float4*)(&acc[0]);
    *(float4*)(&part[wave][8 * lane + 4]) = *(float4*)(&acc[4]);
    __syncthreads();
    float p0 = part[0][2*t] + part[1][2*t] + part[2][2*t] + part[3][2*t];
    float p1 = part[0][2*t+1] + part[1][2*t+1] + part[2][2*t+1] + part[3][2*t+1];
    float* dst = partial + ((size_t)b * LCHUNKS + chunk) * OUTN;
    *(float2*)(dst + 2 * t) = make_float2(p0, p1);
}

// ---------------- Stage B: reduce 32 chunk-partials -> out[b][o]
__global__ __launch_bounds__(256) void pool_reduce(const float* __restrict__ partial,
                                                   float* __restrict__ out) {
    int b = blockIdx.x, t = threadIdx.x;
    const float* src = partial + (size_t)b * LCHUNKS * OUTN;
    float s0 = 0.f, s1 = 0.f;
    for (int c = 0; c < LCHUNKS; c++) {
        float2 v = *(const float2*)(src + (size_t)c * OUTN + 2 * t);
        s0 += v.x; s1 += v.y;
    }
    *(float2*)(out + (size_t)b * OUTN + 2 * t) = make_float2(s0 * (1.f / LEN), s1 * (1.f / LEN));
}

extern "C" void kernel_launch(void* const* d_in, const int* in_sizes, int n_in,
                              void* d_out, int out_size, void* d_ws, size_t ws_size,
                              hipStream_t stream) {
    const float* x       = (const float*)d_in[0];
    const float* Win     = (const float*)d_in[1];
    const float* bin     = (const float*)d_in[2];
    const float* coeffs1 = (const float*)d_in[3];
    const float* bias1   = (const float*)d_in[4];
    const float* g1      = (const float*)d_in[5];
    const float* beta1   = (const float*)d_in[6];
    const float* coeffs2 = (const float*)d_in[7];
    const float* bias2   = (const float*)d_in[8];
    const float* g2      = (const float*)d_in[9];
    const float* beta2   = (const float*)d_in[10];
    float* out = (float*)d_out;

    char* ws = (char*)d_ws;
    unsigned short* Hpow = (unsigned short*)ws;                         // 100,663,296 B
    char* p1 = ws + (size_t)MTOT * KTOT * 2;
    unsigned short* y1   = (unsigned short*)p1;                         // 33,554,432 B
    unsigned short* y2   = (unsigned short*)p1;                         // alias (16 MB of it)
    char* p2 = p1 + (size_t)MTOT * HIDN * 2;
    unsigned short* W1T  = (unsigned short*)p2;                         // 6,291,456 B
    char* p3 = p2 + (size_t)HIDN * KTOT * 2;
    unsigned short* W2T  = (unsigned short*)p3;                         // 3,145,728 B
    char* p4 = p3 + (size_t)OUTN * KTOT * 2;
    float* b1e = (float*)p4;                                            // 4 KB
    float* b2e = (float*)(p4 + HIDN * sizeof(float));                   // 2 KB
    char* p5 = p4 + (HIDN + OUTN) * sizeof(float);
    unsigned short* xT   = (unsigned short*)p5;                         // 2,097,152 B
    char* p6 = p5 + (size_t)MTOT * CIN * 2;
    unsigned short* WinT = (unsigned short*)p6;                         // 131,072 B
    unsigned short* G2pow = Hpow;    // alias: Hpow dead after GEMM1
    float* partial = (float*)W1T;    // alias: W1T dead after GEMM1 (needs 1 MB)

    prep_all<<<1808, 256, 0, stream>>>(coeffs1, bias1, coeffs2, bias2, x, Win,
                                       W1T, b1e, W2T, b2e, xT, WinT);
    proj_mfma<<<dim3(MTOT / 128, HIDN / 128), 256, 0, stream>>>(xT, WinT, bin, Hpow);
    mfma_gemm<HIDN, true><<<dim3(MTOT / 128, HIDN / 128), 256, 0, stream>>>(Hpow, W1T, b1e, y1);
    ln_gelu<<<MTOT / 2, 256, 0, stream>>>(y1, g1, beta1, G2pow);
    mfma_gemm<OUTN, true><<<dim3(MTOT / 128, OUTN / 128), 256, 0, stream>>>(G2pow, W2T, b2e, y2);
    ln_pool_partial<<<dim3(Bsz, LCHUNKS), 256, 0, stream>>>(y2, g2, beta2, partial);
    pool_reduce<<<Bsz, 256, 0, stream>>>(partial, out);
}

// Round 7
// 288.932 us; speedup vs baseline: 1.6824x; 1.0842x over previous
//
#include <hip/hip_runtime.h>
#include <math.h>

#define Bsz  16
#define CIN  64
#define LEN  1024
#define HIDN 1024
#define OUTN 512
#define MTOT (Bsz*LEN)   // 16384
#define KTOT (3*HIDN)    // 3072 (GEMM2)
#define KT1  (2*HIDN + CIN)  // 2112 (GEMM1: [h^2 | h^3 | x])
#define LCHUNKS 32
#define LROWS   (LEN/LCHUNKS)  // 32 rows per block

typedef __attribute__((ext_vector_type(8))) short bf16x8;
typedef __attribute__((ext_vector_type(16))) float f32x16;

__device__ __forceinline__ unsigned short f2bf(float x) {
    union { float f; unsigned int u; } v; v.f = x;
    unsigned int r = v.u + 0x7fff + ((v.u >> 16) & 1);   // RNE
    return (unsigned short)(r >> 16);
}
__device__ __forceinline__ float bf2f(unsigned short u) {
    union { unsigned int u; float f; } v; v.u = ((unsigned int)u) << 16;
    return v.f;
}
__device__ __forceinline__ void gload_lds16(const void* g, void* l) {
    __builtin_amdgcn_global_load_lds((const __attribute__((address_space(1))) void*)g,
                                     (__attribute__((address_space(3))) void*)l, 16, 0, 0);
}

// ---------------- prep_all:
//  [0,1024)      coeffs1 row o -> W1T[o] = [C2 | C3] (stride KT1), b1e = bias1 + sum C0
//  [1024,1536)   coeffs2 row o -> W2T[o] = [C1|C2|C3] (stride KTOT), b2e
//  [1536,1792)   x (B,C,L) 64x64 transpose -> xT[b][l][c] bf16
//  [1792,1808)   Win (C,H) 64x64 transpose -> WinT[h][c] bf16
__global__ __launch_bounds__(256) void prep_all(const float* __restrict__ coeffs1,
                                                const float* __restrict__ bias1,
                                                const float* __restrict__ coeffs2,
                                                const float* __restrict__ bias2,
                                                const float* __restrict__ x,
                                                const float* __restrict__ Win,
                                                unsigned short* __restrict__ W1T,
                                                float* __restrict__ b1e,
                                                unsigned short* __restrict__ W2T,
                                                float* __restrict__ b2e,
                                                unsigned short* __restrict__ xT,
                                                unsigned short* __restrict__ WinT) {
    __shared__ float sm[64 * 65];
    int bid = blockIdx.x, t = threadIdx.x;
    if (bid < 1024) {
        int o = bid;
        float s = 0.f;
        unsigned short* wrow = W1T + (size_t)o * KT1;
        for (int c = t; c < HIDN; c += 256) {
            float4 v = *(const float4*)(coeffs1 + ((size_t)o * HIDN + c) * 4);
            s += v.x;                       // order-0 -> bias
            wrow[c]        = f2bf(v.z);     // C2 plane
            wrow[HIDN + c] = f2bf(v.w);     // C3 plane  (v.y = C1 handled by wc1_kernel)
        }
        for (int off = 32; off > 0; off >>= 1) s += __shfl_down(s, off, 64);
        if ((t & 63) == 0) sm[t >> 6] = s;
        __syncthreads();
        if (t == 0) b1e[o] = bias1[o] + sm[0] + sm[1] + sm[2] + sm[3];
    } else if (bid < 1536) {
        int o = bid - 1024;
        float s = 0.f;
        unsigned short* wrow = W2T + (size_t)o * KTOT;
        for (int c = t; c < HIDN; c += 256) {
            float4 v = *(const float4*)(coeffs2 + ((size_t)o * HIDN + c) * 4);
            s += v.x;
            wrow[c]            = f2bf(v.y);
            wrow[HIDN + c]     = f2bf(v.z);
            wrow[2 * HIDN + c] = f2bf(v.w);
        }
        for (int off = 32; off > 0; off >>= 1) s += __shfl_down(s, off, 64);
        if ((t & 63) == 0) sm[t >> 6] = s;
        __syncthreads();
        if (t == 0) b2e[o] = bias2[o] + sm[0] + sm[1] + sm[2] + sm[3];
    } else {
        const float* src; unsigned short* dstbase; size_t src_rstride;
        int c0;
        if (bid < 1792) {
            int tile = bid - 1536; int b = tile >> 4; c0 = (tile & 15) * 64;
            src = x + (size_t)b * CIN * LEN;  src_rstride = LEN;
            dstbase = xT + ((size_t)b * LEN + c0) * CIN;
        } else {
            int tile = bid - 1792; c0 = tile * 64;
            src = Win; src_rstride = HIDN;
            dstbase = WinT + (size_t)c0 * CIN;
        }
#pragma unroll
        for (int it = 0; it < 4; it++) {
            int idx = t + it * 256;
            int c = idx >> 4, q = idx & 15;
            float4 v = *(const float4*)(src + (size_t)c * src_rstride + c0 + q * 4);
            sm[c * 65 + q * 4 + 0] = v.x;
            sm[c * 65 + q * 4 + 1] = v.y;
            sm[c * 65 + q * 4 + 2] = v.z;
            sm[c * 65 + q * 4 + 3] = v.w;
        }
        __syncthreads();
        int ll = t >> 2, cg = (t & 3) * 16;
        unsigned short* dst = dstbase + (size_t)ll * CIN + cg;
#pragma unroll
        for (int j = 0; j < 4; j++) {
            int c = cg + j * 4;
            ushort4 w = { f2bf(sm[(c + 0) * 65 + ll]), f2bf(sm[(c + 1) * 65 + ll]),
                          f2bf(sm[(c + 2) * 65 + ll]), f2bf(sm[(c + 3) * 65 + ll]) };
            *(ushort4*)(dst + j * 4) = w;
        }
    }
}

// ---------------- wc1: W1T[o][2048+cin] = (Win @ C1)[cin,o];  b1e[o] += bin . C1[:,o]
// One block per o. WinT rows give coalesced 64-lane reads.
__global__ __launch_bounds__(256) void wc1_kernel(const float* __restrict__ coeffs1,
                                                  const unsigned short* __restrict__ WinT,
                                                  const float* __restrict__ bin,
                                                  unsigned short* __restrict__ W1T,
                                                  float* __restrict__ b1e) {
    __shared__ float c1s[HIDN];
    __shared__ float part[4][64];
    __shared__ float pbred[4];
    int o = blockIdx.x, t = threadIdx.x, lane = t & 63, wave = t >> 6;
    for (int c = t; c < HIDN; c += 256)
        c1s[c] = coeffs1[((size_t)o * HIDN + c) * 4 + 1];
    __syncthreads();
    float acc = 0.f;
    int cbase = wave * 256;
    for (int c = cbase; c < cbase + 256; c++)
        acc += bf2f(WinT[c * CIN + lane]) * c1s[c];
    part[wave][lane] = acc;
    float pb = 0.f;
    for (int c = t; c < HIDN; c += 256) pb += bin[c] * c1s[c];
    for (int off = 32; off > 0; off >>= 1) pb += __shfl_down(pb, off, 64);
    if (lane == 0) pbred[wave] = pb;
    __syncthreads();
    if (t < 64) {
        float v = part[0][t] + part[1][t] + part[2][t] + part[3][t];
        W1T[(size_t)o * KT1 + 2 * HIDN + t] = f2bf(v);
    }
    if (t == 0) b1e[o] += pbred[0] + pbred[1] + pbred[2] + pbred[3];
}

// ---------------- proj_mfma: h = xT @ WinT^T + bin (K=64); write A1 planes [h^2|h^3];
// blocks with n0==0 also copy the x-tail into A1[:, 2048:2112].
__global__ __launch_bounds__(256) void proj_mfma(const unsigned short* __restrict__ xT,
                                                 const unsigned short* __restrict__ WinT,
                                                 const float* __restrict__ bin,
                                                 unsigned short* __restrict__ A1) {
    __shared__ unsigned short smem[2 * 128 * 64];   // staging; reused as 128x128 ht
    unsigned short* As = smem;
    unsigned short* Bs = smem + 128 * 64;
    unsigned short* ht = smem;
    int t = threadIdx.x, lane = t & 63, wave = t >> 6;
    int m0 = blockIdx.x * 128, n0 = blockIdx.y * 128;
    int srow = lane >> 3, sgcc = (lane & 7) ^ srow;
    const unsigned short* Ab = xT + (size_t)m0 * CIN;
    const unsigned short* Bb = WinT + (size_t)n0 * CIN;

    f32x16 acc[2][2] = {};
    int wr = (wave >> 1) * 64, wc = (wave & 1) * 64;
    int row32 = lane & 31, half = lane >> 5;

#pragma unroll
    for (int j = 0; j < 4; j++) {
        int rgrp = wave * 32 + j * 8;
        gload_lds16(Ab + (size_t)(rgrp + srow) * CIN + sgcc * 8, As + rgrp * 64);
        gload_lds16(Bb + (size_t)(rgrp + srow) * CIN + sgcc * 8, Bs + rgrp * 64);
    }
    __syncthreads();
#pragma unroll
    for (int ks = 0; ks < 4; ks++) {
        int cidx = ks * 2 + half;
        bf16x8 af[2], bf[2];
#pragma unroll
        for (int mt = 0; mt < 2; mt++) {
            int r = wr + mt * 32 + row32;
            af[mt] = *(const bf16x8*)(As + r * 64 + ((cidx ^ (r & 7)) << 3));
        }
#pragma unroll
        for (int nt = 0; nt < 2; nt++) {
            int c = wc + nt * 32 + row32;
            bf[nt] = *(const bf16x8*)(Bs + c * 64 + ((cidx ^ (c & 7)) << 3));
        }
#pragma unroll
        for (int mt = 0; mt < 2; mt++)
#pragma unroll
            for (int nt = 0; nt < 2; nt++)
                acc[mt][nt] = __builtin_amdgcn_mfma_f32_32x32x16_bf16(af[mt], bf[nt], acc[mt][nt], 0, 0, 0);
    }
    __syncthreads();   // safe to reuse smem
#pragma unroll
    for (int nt = 0; nt < 2; nt++) {
        int ocl = wc + nt * 32 + row32;
        float bo = bin[n0 + ocl];
#pragma unroll
        for (int mt = 0; mt < 2; mt++) {
#pragma unroll
            for (int reg = 0; reg < 16; reg++) {
                int rl = wr + mt * 32 + (reg & 3) + 8 * (reg >> 2) + 4 * half;
                ht[rl * 128 + ocl] = f2bf(acc[mt][nt][reg] + bo);
            }
        }
    }
    __syncthreads();
    // write h^2, h^3 planes with 16B stores
#pragma unroll
    for (int p = 0; p < 8; p++) {
        int r = p * 16 + (t >> 4);
        int c = (t & 15) * 8;
        bf16x8 hv = *(const bf16x8*)(ht + r * 128 + c);
        bf16x8 h2v, h3v;
#pragma unroll
        for (int j = 0; j < 8; j++) {
            float f = bf2f((unsigned short)hv[j]);
            float f2 = f * f;
            h2v[j] = (short)f2bf(f2);
            h3v[j] = (short)f2bf(f2 * f);
        }
        unsigned short* d = A1 + (size_t)(m0 + r) * KT1 + n0 + c;
        *(bf16x8*)(d)        = h2v;
        *(bf16x8*)(d + HIDN) = h3v;
    }
    // x-tail copy: A1[m][2048..2111] = xT[m][0..63]
    if (n0 == 0) {
#pragma unroll
        for (int it = 0; it < 4; it++) {
            int idx = t + it * 256;          // 0..1023 = 128 rows x 8 chunks
            int r = idx >> 3, cc = (idx & 7) * 8;
            bf16x8 v = *(const bf16x8*)(xT + (size_t)(m0 + r) * CIN + cc);
            *(bf16x8*)(A1 + (size_t)(m0 + r) * KT1 + 2 * HIDN + cc) = v;
        }
    }
}

// ---------------- MFMA GEMM (32x32x16): Y[M][N] = A(M x KT) @ BT(N x KT)^T + beff
template<int N, int KT, bool BF16OUT>
__global__ __launch_bounds__(256) void mfma_gemm(const unsigned short* __restrict__ A,
                                                 const unsigned short* __restrict__ BT,
                                                 const float* __restrict__ beff,
                                                 void* __restrict__ Yv) {
    __shared__ unsigned short As[128 * 64];
    __shared__ unsigned short Bs[128 * 64];
    int t = threadIdx.x;
    int lane = t & 63, wave = t >> 6;
    int m0 = blockIdx.x * 128, n0 = blockIdx.y * 128;
    const unsigned short* Ab = A + (size_t)m0 * KT;
    const unsigned short* Bb = BT + (size_t)n0 * KT;

    int srow = lane >> 3;
    int sgcc = (lane & 7) ^ srow;

    f32x16 acc[2][2] = {};
    int wr = (wave >> 1) * 64;
    int wc = (wave & 1) * 64;
    int row32 = lane & 31, half = lane >> 5;

    for (int k0 = 0; k0 < KT; k0 += 64) {
#pragma unroll
        for (int j = 0; j < 4; j++) {
            int rgrp = wave * 32 + j * 8;
            gload_lds16(Ab + ((size_t)(rgrp + srow) * KT + k0 + sgcc * 8), As + rgrp * 64);
            gload_lds16(Bb + ((size_t)(rgrp + srow) * KT + k0 + sgcc * 8), Bs + rgrp * 64);
        }
        __syncthreads();
#pragma unroll
        for (int ks = 0; ks < 4; ks++) {
            int cidx = ks * 2 + half;
            bf16x8 af[2], bf[2];
#pragma unroll
            for (int mt = 0; mt < 2; mt++) {
                int r = wr + mt * 32 + row32;
                af[mt] = *(const bf16x8*)(As + r * 64 + ((cidx ^ (r & 7)) << 3));
            }
#pragma unroll
            for (int nt = 0; nt < 2; nt++) {
                int c = wc + nt * 32 + row32;
                bf[nt] = *(const bf16x8*)(Bs + c * 64 + ((cidx ^ (c & 7)) << 3));
            }
#pragma unroll
            for (int mt = 0; mt < 2; mt++)
#pragma unroll
                for (int nt = 0; nt < 2; nt++)
                    acc[mt][nt] = __builtin_amdgcn_mfma_f32_32x32x16_bf16(af[mt], bf[nt], acc[mt][nt], 0, 0, 0);
        }
        __syncthreads();
    }
#pragma unroll
    for (int nt = 0; nt < 2; nt++) {
        int oc = n0 + wc + nt * 32 + row32;
        float bo = beff[oc];
#pragma unroll
        for (int mt = 0; mt < 2; mt++) {
#pragma unroll
            for (int reg = 0; reg < 16; reg++) {
                int rl = (reg & 3) + 8 * (reg >> 2) + 4 * half;
                int mr = m0 + wr + mt * 32 + rl;
                float v = acc[mt][nt][reg] + bo;
                if (BF16OUT) ((unsigned short*)Yv)[(size_t)mr * N + oc] = f2bf(v);
                else         ((float*)Yv)[(size_t)mr * N + oc] = v;
            }
        }
    }
}

// ---------------- LN(1024) + exact GELU, emit bf16 powers; 2 rows/block, 16B ld/st
__global__ __launch_bounds__(256) void ln_gelu(const unsigned short* __restrict__ y1,
                                               const float* __restrict__ g,
                                               const float* __restrict__ be,
                                               unsigned short* __restrict__ Gpow) {
    __shared__ float2 red[2][2];
    int t = threadIdx.x;
    int rhalf = t >> 7, l = t & 127, wid = (t >> 6) & 1;
    int m = blockIdx.x * 2 + rhalf;
    bf16x8 u = *(const bf16x8*)(y1 + (size_t)m * HIDN + l * 8);
    float v[8];
    float s = 0.f, ss = 0.f;
#pragma unroll
    for (int j = 0; j < 8; j++) {
        v[j] = bf2f((unsigned short)u[j]);
        s += v[j]; ss += v[j] * v[j];
    }
    for (int off = 32; off > 0; off >>= 1) {
        s  += __shfl_down(s, off, 64);
        ss += __shfl_down(ss, off, 64);
    }
    if ((t & 63) == 0) red[rhalf][wid] = make_float2(s, ss);
    __syncthreads();
    float sT  = red[rhalf][0].x + red[rhalf][1].x;
    float ssT = red[rhalf][0].y + red[rhalf][1].y;
    float mu = sT * (1.f / HIDN);
    float var = ssT * (1.f / HIDN) - mu * mu;
    float rs = rsqrtf(var + 1e-5f);
    float4 gA = *(const float4*)(g + l * 8),  gB = *(const float4*)(g + l * 8 + 4);
    float4 bA = *(const float4*)(be + l * 8), bB = *(const float4*)(be + l * 8 + 4);
    float gv[8] = { gA.x, gA.y, gA.z, gA.w, gB.x, gB.y, gB.z, gB.w };
    float bv[8] = { bA.x, bA.y, bA.z, bA.w, bB.x, bB.y, bB.z, bB.w };
    bf16x8 p1, p2, p3;
#pragma unroll
    for (int j = 0; j < 8; j++) {
        float xn = (v[j] - mu) * rs * gv[j] + bv[j];
        float gl = xn * 0.5f * (1.f + erff(xn * 0.70710678118654752f));
        float g2 = gl * gl;
        p1[j] = (short)f2bf(gl);
        p2[j] = (short)f2bf(g2);
        p3[j] = (short)f2bf(g2 * gl);
    }
    unsigned short* dst = Gpow + (size_t)m * KTOT + l * 8;
    *(bf16x8*)(dst)            = p1;
    *(bf16x8*)(dst + HIDN)     = p2;
    *(bf16x8*)(dst + 2 * HIDN) = p3;
}

// ---------------- Stage A: LN(512) per row (bf16 y2) + partial mean over L-chunk
__global__ __launch_bounds__(256) void ln_pool_partial(const unsigned short* __restrict__ y2,
                                                       const float* __restrict__ g,
                                                       const float* __restrict__ be,
                                                       float* __restrict__ partial) {
    __shared__ float part[4][OUTN];
    int t = threadIdx.x, lane = t & 63, wave = t >> 6;
    int b = blockIdx.x, chunk = blockIdx.y;
    int mbase = b * LEN + chunk * LROWS;

    float4 gA = *(const float4*)(g + 8 * lane),  gB = *(const float4*)(g + 8 * lane + 4);
    float4 bA = *(const float4*)(be + 8 * lane), bB = *(const float4*)(be + 8 * lane + 4);
    float gv[8] = { gA.x, gA.y, gA.z, gA.w, gB.x, gB.y, gB.z, gB.w };
    float bv[8] = { bA.x, bA.y, bA.z, bA.w, bB.x, bB.y, bB.z, bB.w };

    float acc[8] = {0.f, 0.f, 0.f, 0.f, 0.f, 0.f, 0.f, 0.f};
    for (int rr = wave; rr < LROWS; rr += 4) {
        bf16x8 u = *(const bf16x8*)(y2 + (size_t)(mbase + rr) * OUTN + 8 * lane);
        float v[8];
        float s = 0.f, ss = 0.f;
#pragma unroll
        for (int j = 0; j < 8; j++) {
            v[j] = bf2f((unsigned short)u[j]);
            s += v[j]; ss += v[j] * v[j];
        }
        for (int off = 32; off > 0; off >>= 1) {
            s  += __shfl_down(s, off, 64);
            ss += __shfl_down(ss, off, 64);
        }
        s  = __shfl(s, 0, 64);
        ss = __shfl(ss, 0, 64);
        float mu = s * (1.f / OUTN);
        float var = ss * (1.f / OUTN) - mu * mu;
        float rs = rsqrtf(var + 1e-5f);
#pragma unroll
        for (int j = 0; j < 8; j++)
            acc[j] += (v[j] - mu) * rs * gv[j] + bv[j];
    }
    *(float4*)(&part[wave][8 * lane])     = *(float4*)(&acc[0]);
    *(float4*)(&part[wave][8 * lane + 4]) = *(float4*)(&acc[4]);
    __syncthreads();
    float p0 = part[0][2*t] + part[1][2*t] + part[2][2*t] + part[3][2*t];
    float p1 = part[0][2*t+1] + part[1][2*t+1] + part[2][2*t+1] + part[3][2*t+1];
    float* dst = partial + ((size_t)b * LCHUNKS + chunk) * OUTN;
    *(float2*)(dst + 2 * t) = make_float2(p0, p1);
}

// ---------------- Stage B: reduce 32 chunk-partials -> out[b][o]
__global__ __launch_bounds__(256) void pool_reduce(const float* __restrict__ partial,
                                                   float* __restrict__ out) {
    int b = blockIdx.x, t = threadIdx.x;
    const float* src = partial + (size_t)b * LCHUNKS * OUTN;
    float s0 = 0.f, s1 = 0.f;
    for (int c = 0; c < LCHUNKS; c++) {
        float2 v = *(const float2*)(src + (size_t)c * OUTN + 2 * t);
        s0 += v.x; s1 += v.y;
    }
    *(float2*)(out + (size_t)b * OUTN + 2 * t) = make_float2(s0 * (1.f / LEN), s1 * (1.f / LEN));
}

extern "C" void kernel_launch(void* const* d_in, const int* in_sizes, int n_in,
                              void* d_out, int out_size, void* d_ws, size_t ws_size,
                              hipStream_t stream) {
    const float* x       = (const float*)d_in[0];
    const float* Win     = (const float*)d_in[1];
    const float* bin     = (const float*)d_in[2];
    const float* coeffs1 = (const float*)d_in[3];
    const float* bias1   = (const float*)d_in[4];
    const float* g1      = (const float*)d_in[5];
    const float* beta1   = (const float*)d_in[6];
    const float* coeffs2 = (const float*)d_in[7];
    const float* bias2   = (const float*)d_in[8];
    const float* g2      = (const float*)d_in[9];
    const float* beta2   = (const float*)d_in[10];
    float* out = (float*)d_out;

    char* ws = (char*)d_ws;
    // A1 (M x 2112 bf16) and Gpow (M x 3072 bf16) share the big region (A1 dead after GEMM1)
    unsigned short* A1   = (unsigned short*)ws;
    unsigned short* Gpow = (unsigned short*)ws;                         // 100,663,296 B (max)
    char* p1 = ws + (size_t)MTOT * KTOT * 2;
    unsigned short* y1   = (unsigned short*)p1;                         // 33,554,432 B
    unsigned short* y2   = (unsigned short*)p1;                         // alias (16 MB)
    char* p2 = p1 + (size_t)MTOT * HIDN * 2;
    unsigned short* W1T  = (unsigned short*)p2;                         // 1024*2112*2 = 4,325,376 B
    char* p3 = p2 + (size_t)HIDN * KT1 * 2;
    unsigned short* W2T  = (unsigned short*)p3;                         // 512*3072*2 = 3,145,728 B
    char* p4 = p3 + (size_t)OUTN * KTOT * 2;
    float* b1e = (float*)p4;                                            // 4 KB
    float* b2e = (float*)(p4 + HIDN * sizeof(float));                   // 2 KB
    char* p5 = p4 + (HIDN + OUTN) * sizeof(float);
    unsigned short* xT   = (unsigned short*)p5;                         // 2,097,152 B
    char* p6 = p5 + (size_t)MTOT * CIN * 2;
    unsigned short* WinT = (unsigned short*)p6;                         // 131,072 B
    float* partial = (float*)W1T;    // alias: W1T dead after GEMM1 (needs 1 MB)

    prep_all<<<1808, 256, 0, stream>>>(coeffs1, bias1, coeffs2, bias2, x, Win,
                                       W1T, b1e, W2T, b2e, xT, WinT);
    wc1_kernel<<<HIDN, 256, 0, stream>>>(coeffs1, WinT, bin, W1T, b1e);
    proj_mfma<<<dim3(MTOT / 128, HIDN / 128), 256, 0, stream>>>(xT, WinT, bin, A1);
    mfma_gemm<HIDN, KT1, true><<<dim3(MTOT / 128, HIDN / 128), 256, 0, stream>>>(A1, W1T, b1e, y1);
    ln_gelu<<<MTOT / 2, 256, 0, stream>>>(y1, g1, beta1, Gpow);
    mfma_gemm<OUTN, KTOT, true><<<dim3(MTOT / 128, OUTN / 128), 256, 0, stream>>>(Gpow, W2T, b2e, y2);
    ln_pool_partial<<<dim3(Bsz, LCHUNKS), 256, 0, stream>>>(y2, g2, beta2, partial);
    pool_reduce<<<Bsz, 256, 0, stream>>>(partial, out);
}

// Round 8
// 286.916 us; speedup vs baseline: 1.6943x; 1.0070x over previous
//
#include <hip/hip_runtime.h>
#include <hip/hip_bf16.h>
#include <math.h>

#define Bsz  16
#define CIN  64
#define LEN  1024
#define HIDN 1024
#define OUTN 512
#define MTOT (Bsz*LEN)   // 16384
#define KTOT (3*HIDN)    // 3072 (W2T plane stride basis)
#define KT1  (2*HIDN + CIN)  // 2112 (GEMM1: [h^2 | h^3 | x])
#define LCHUNKS 32
#define LROWS   (LEN/LCHUNKS)  // 32 rows per block

typedef __attribute__((ext_vector_type(8))) short bf16x8;
typedef __attribute__((ext_vector_type(16))) float f32x16;

__device__ __forceinline__ unsigned short f2bf(float x) {
    union { float f; unsigned int u; } v; v.f = x;
    unsigned int r = v.u + 0x7fff + ((v.u >> 16) & 1);   // RNE
    return (unsigned short)(r >> 16);
}
__device__ __forceinline__ float bf2f(unsigned short u) {
    union { unsigned int u; float f; } v; v.u = ((unsigned int)u) << 16;
    return v.f;
}
__device__ __forceinline__ void gload_lds16(const void* g, void* l) {
    __builtin_amdgcn_global_load_lds((const __attribute__((address_space(1))) void*)g,
                                     (__attribute__((address_space(3))) void*)l, 16, 0, 0);
}
// a (bf16x8) -> a2=a^2, a3=a^3 via packed RNE converts
__device__ __forceinline__ void powfrags(const bf16x8& a, bf16x8& a2, bf16x8& a3) {
#pragma unroll
    for (int j = 0; j < 4; j++) {
        float f0 = bf2f((unsigned short)a[2 * j]);
        float f1 = bf2f((unsigned short)a[2 * j + 1]);
        float s0 = f0 * f0, s1 = f1 * f1;
        __hip_bfloat162 p2 = __float22bfloat162_rn(float2{ s0, s1 });
        __hip_bfloat162 p3 = __float22bfloat162_rn(float2{ s0 * f0, s1 * f1 });
        ((unsigned int*)&a2)[j] = *(unsigned int*)&p2;
        ((unsigned int*)&a3)[j] = *(unsigned int*)&p3;
    }
}

// ---------------- prep_all:
//  [0,1024)      coeffs1 row o -> W1T[o] = [C2 | C3] (stride KT1), b1e = bias1 + sum C0
//  [1024,1536)   coeffs2 row o -> W2T[o] = [C1|C2|C3] (stride KTOT), b2e
//  [1536,1792)   x (B,C,L) 64x64 transpose -> xT[b][l][c] bf16
//  [1792,1808)   Win (C,H) 64x64 transpose -> WinT[h][c] bf16
__global__ __launch_bounds__(256) void prep_all(const float* __restrict__ coeffs1,
                                                const float* __restrict__ bias1,
                                                const float* __restrict__ coeffs2,
                                                const float* __restrict__ bias2,
                                                const float* __restrict__ x,
                                                const float* __restrict__ Win,
                                                unsigned short* __restrict__ W1T,
                                                float* __restrict__ b1e,
                                                unsigned short* __restrict__ W2T,
                                                float* __restrict__ b2e,
                                                unsigned short* __restrict__ xT,
                                                unsigned short* __restrict__ WinT) {
    __shared__ float sm[64 * 65];
    int bid = blockIdx.x, t = threadIdx.x;
    if (bid < 1024) {
        int o = bid;
        float s = 0.f;
        unsigned short* wrow = W1T + (size_t)o * KT1;
        for (int c = t; c < HIDN; c += 256) {
            float4 v = *(const float4*)(coeffs1 + ((size_t)o * HIDN + c) * 4);
            s += v.x;                       // order-0 -> bias
            wrow[c]        = f2bf(v.z);     // C2 plane
            wrow[HIDN + c] = f2bf(v.w);     // C3 plane  (C1 handled in proj_mfma tail)
        }
        for (int off = 32; off > 0; off >>= 1) s += __shfl_down(s, off, 64);
        if ((t & 63) == 0) sm[t >> 6] = s;
        __syncthreads();
        if (t == 0) b1e[o] = bias1[o] + sm[0] + sm[1] + sm[2] + sm[3];
    } else if (bid < 1536) {
        int o = bid - 1024;
        float s = 0.f;
        unsigned short* wrow = W2T + (size_t)o * KTOT;
        for (int c = t; c < HIDN; c += 256) {
            float4 v = *(const float4*)(coeffs2 + ((size_t)o * HIDN + c) * 4);
            s += v.x;
            wrow[c]            = f2bf(v.y);
            wrow[HIDN + c]     = f2bf(v.z);
            wrow[2 * HIDN + c] = f2bf(v.w);
        }
        for (int off = 32; off > 0; off >>= 1) s += __shfl_down(s, off, 64);
        if ((t & 63) == 0) sm[t >> 6] = s;
        __syncthreads();
        if (t == 0) b2e[o] = bias2[o] + sm[0] + sm[1] + sm[2] + sm[3];
    } else {
        const float* src; unsigned short* dstbase; size_t src_rstride;
        int c0;
        if (bid < 1792) {
            int tile = bid - 1536; int b = tile >> 4; c0 = (tile & 15) * 64;
            src = x + (size_t)b * CIN * LEN;  src_rstride = LEN;
            dstbase = xT + ((size_t)b * LEN + c0) * CIN;
        } else {
            int tile = bid - 1792; c0 = tile * 64;
            src = Win; src_rstride = HIDN;
            dstbase = WinT + (size_t)c0 * CIN;
        }
#pragma unroll
        for (int it = 0; it < 4; it++) {
            int idx = t + it * 256;
            int c = idx >> 4, q = idx & 15;
            float4 v = *(const float4*)(src + (size_t)c * src_rstride + c0 + q * 4);
            sm[c * 65 + q * 4 + 0] = v.x;
            sm[c * 65 + q * 4 + 1] = v.y;
            sm[c * 65 + q * 4 + 2] = v.z;
            sm[c * 65 + q * 4 + 3] = v.w;
        }
        __syncthreads();
        int ll = t >> 2, cg = (t & 3) * 16;
        unsigned short* dst = dstbase + (size_t)ll * CIN + cg;
#pragma unroll
        for (int j = 0; j < 4; j++) {
            int c = cg + j * 4;
            ushort4 w = { f2bf(sm[(c + 0) * 65 + ll]), f2bf(sm[(c + 1) * 65 + ll]),
                          f2bf(sm[(c + 2) * 65 + ll]), f2bf(sm[(c + 3) * 65 + ll]) };
            *(ushort4*)(dst + j * 4) = w;
        }
    }
}

// ---------------- proj_mfma: h = xT @ WinT^T + bin (K=64); write A1 planes [h^2|h^3];
// n0==0 blocks copy the x-tail. Tail work (all blocks): former wc1 for o = bx*8+by:
//   W1T[o][2048+cin] = sum_c Win[cin][c]*C1[o][c];  b1e[o] += bin.C1[o]
__global__ __launch_bounds__(256) void proj_mfma(const unsigned short* __restrict__ xT,
                                                 const unsigned short* __restrict__ WinT,
                                                 const float* __restrict__ bin,
                                                 unsigned short* __restrict__ A1,
                                                 const float* __restrict__ coeffs1,
                                                 unsigned short* __restrict__ W1T,
                                                 float* __restrict__ b1e) {
    __shared__ unsigned short smem[2 * 128 * 64];   // staging; reused as ht; reused for wc1 tail
    unsigned short* As = smem;
    unsigned short* Bs = smem + 128 * 64;
    unsigned short* ht = smem;
    int t = threadIdx.x, lane = t & 63, wave = t >> 6;
    int m0 = blockIdx.x * 128, n0 = blockIdx.y * 128;
    int srow = lane >> 3, sgcc = (lane & 7) ^ srow;
    const unsigned short* Ab = xT + (size_t)m0 * CIN;
    const unsigned short* Bb = WinT + (size_t)n0 * CIN;

    f32x16 acc[2][2] = {};
    int wr = (wave >> 1) * 64, wc = (wave & 1) * 64;
    int row32 = lane & 31, half = lane >> 5;

#pragma unroll
    for (int j = 0; j < 4; j++) {
        int rgrp = wave * 32 + j * 8;
        gload_lds16(Ab + (size_t)(rgrp + srow) * CIN + sgcc * 8, As + rgrp * 64);
        gload_lds16(Bb + (size_t)(rgrp + srow) * CIN + sgcc * 8, Bs + rgrp * 64);
    }
    __syncthreads();
#pragma unroll
    for (int ks = 0; ks < 4; ks++) {
        int cidx = ks * 2 + half;
        bf16x8 af[2], bf[2];
#pragma unroll
        for (int mt = 0; mt < 2; mt++) {
            int r = wr + mt * 32 + row32;
            af[mt] = *(const bf16x8*)(As + r * 64 + ((cidx ^ (r & 7)) << 3));
        }
#pragma unroll
        for (int nt = 0; nt < 2; nt++) {
            int c = wc + nt * 32 + row32;
            bf[nt] = *(const bf16x8*)(Bs + c * 64 + ((cidx ^ (c & 7)) << 3));
        }
#pragma unroll
        for (int mt = 0; mt < 2; mt++)
#pragma unroll
            for (int nt = 0; nt < 2; nt++)
                acc[mt][nt] = __builtin_amdgcn_mfma_f32_32x32x16_bf16(af[mt], bf[nt], acc[mt][nt], 0, 0, 0);
    }
    __syncthreads();   // safe to reuse smem
#pragma unroll
    for (int nt = 0; nt < 2; nt++) {
        int ocl = wc + nt * 32 + row32;
        float bo = bin[n0 + ocl];
#pragma unroll
        for (int mt = 0; mt < 2; mt++) {
#pragma unroll
            for (int reg = 0; reg < 16; reg++) {
                int rl = wr + mt * 32 + (reg & 3) + 8 * (reg >> 2) + 4 * half;
                ht[rl * 128 + ocl] = f2bf(acc[mt][nt][reg] + bo);
            }
        }
    }
    __syncthreads();
    // write h^2, h^3 planes with 16B stores
#pragma unroll
    for (int p = 0; p < 8; p++) {
        int r = p * 16 + (t >> 4);
        int c = (t & 15) * 8;
        bf16x8 hv = *(const bf16x8*)(ht + r * 128 + c);
        bf16x8 h2v, h3v;
#pragma unroll
        for (int j = 0; j < 8; j++) {
            float f = bf2f((unsigned short)hv[j]);
            float f2 = f * f;
            h2v[j] = (short)f2bf(f2);
            h3v[j] = (short)f2bf(f2 * f);
        }
        unsigned short* d = A1 + (size_t)(m0 + r) * KT1 + n0 + c;
        *(bf16x8*)(d)        = h2v;
        *(bf16x8*)(d + HIDN) = h3v;
    }
    // x-tail copy: A1[m][2048..2111] = xT[m][0..63]
    if (n0 == 0) {
#pragma unroll
        for (int it = 0; it < 4; it++) {
            int idx = t + it * 256;
            int r = idx >> 3, cc = (idx & 7) * 8;
            bf16x8 v = *(const bf16x8*)(xT + (size_t)(m0 + r) * CIN + cc);
            *(bf16x8*)(A1 + (size_t)(m0 + r) * KT1 + 2 * HIDN + cc) = v;
        }
    }
    // ---- wc1 tail: one o per block ----
    int o = blockIdx.x * 8 + blockIdx.y;     // exactly [0,1024)
    __syncthreads();                          // done with ht
    float* c1s   = (float*)smem;              // 1024 floats
    float* part  = (float*)smem + 1024;       // 4*64
    float* pbred = part + 256;                // 4
    for (int c = t; c < HIDN; c += 256) {
        float4 v = *(const float4*)(coeffs1 + ((size_t)o * HIDN + c) * 4);
        c1s[c] = v.y;
    }
    __syncthreads();
    float a1 = 0.f;
    int cbase = wave * 256;
    for (int c = cbase; c < cbase + 256; c++)
        a1 += bf2f(WinT[c * CIN + lane]) * c1s[c];
    part[wave * 64 + lane] = a1;
    float pb = 0.f;
    for (int c = t; c < HIDN; c += 256) pb += bin[c] * c1s[c];
    for (int off = 32; off > 0; off >>= 1) pb += __shfl_down(pb, off, 64);
    if (lane == 0) pbred[wave] = pb;
    __syncthreads();
    if (t < 64) {
        float v = part[t] + part[64 + t] + part[128 + t] + part[192 + t];
        W1T[(size_t)o * KT1 + 2 * HIDN + t] = f2bf(v);
    }
    if (t == 0) atomicAdd(&b1e[o], pbred[0] + pbred[1] + pbred[2] + pbred[3]);
}

// ---------------- GEMM1 (unchanged structure): Y = A1(M x KT1) @ W1T^T + b1e
template<int N, int KT, bool BF16OUT>
__global__ __launch_bounds__(256) void mfma_gemm(const unsigned short* __restrict__ A,
                                                 const unsigned short* __restrict__ BT,
                                                 const float* __restrict__ beff,
                                                 void* __restrict__ Yv) {
    __shared__ unsigned short As[128 * 64];
    __shared__ unsigned short Bs[128 * 64];
    int t = threadIdx.x;
    int lane = t & 63, wave = t >> 6;
    int m0 = blockIdx.x * 128, n0 = blockIdx.y * 128;
    const unsigned short* Ab = A + (size_t)m0 * KT;
    const unsigned short* Bb = BT + (size_t)n0 * KT;

    int srow = lane >> 3;
    int sgcc = (lane & 7) ^ srow;

    f32x16 acc[2][2] = {};
    int wr = (wave >> 1) * 64;
    int wc = (wave & 1) * 64;
    int row32 = lane & 31, half = lane >> 5;

    for (int k0 = 0; k0 < KT; k0 += 64) {
#pragma unroll
        for (int j = 0; j < 4; j++) {
            int rgrp = wave * 32 + j * 8;
            gload_lds16(Ab + ((size_t)(rgrp + srow) * KT + k0 + sgcc * 8), As + rgrp * 64);
            gload_lds16(Bb + ((size_t)(rgrp + srow) * KT + k0 + sgcc * 8), Bs + rgrp * 64);
        }
        __syncthreads();
#pragma unroll
        for (int ks = 0; ks < 4; ks++) {
            int cidx = ks * 2 + half;
            bf16x8 af[2], bf[2];
#pragma unroll
            for (int mt = 0; mt < 2; mt++) {
                int r = wr + mt * 32 + row32;
                af[mt] = *(const bf16x8*)(As + r * 64 + ((cidx ^ (r & 7)) << 3));
            }
#pragma unroll
            for (int nt = 0; nt < 2; nt++) {
                int c = wc + nt * 32 + row32;
                bf[nt] = *(const bf16x8*)(Bs + c * 64 + ((cidx ^ (c & 7)) << 3));
            }
#pragma unroll
            for (int mt = 0; mt < 2; mt++)
#pragma unroll
                for (int nt = 0; nt < 2; nt++)
                    acc[mt][nt] = __builtin_amdgcn_mfma_f32_32x32x16_bf16(af[mt], bf[nt], acc[mt][nt], 0, 0, 0);
        }
        __syncthreads();
    }
#pragma unroll
    for (int nt = 0; nt < 2; nt++) {
        int oc = n0 + wc + nt * 32 + row32;
        float bo = beff[oc];
#pragma unroll
        for (int mt = 0; mt < 2; mt++) {
#pragma unroll
            for (int reg = 0; reg < 16; reg++) {
                int rl = (reg & 3) + 8 * (reg >> 2) + 4 * half;
                int mr = m0 + wr + mt * 32 + rl;
                float v = acc[mt][nt][reg] + bo;
                if (BF16OUT) ((unsigned short*)Yv)[(size_t)mr * N + oc] = f2bf(v);
                else         ((float*)Yv)[(size_t)mr * N + oc] = v;
            }
        }
    }
}

// ---------------- LN(1024) + exact GELU, emit ONLY g (bf16); 2 rows/block
__global__ __launch_bounds__(256) void ln_gelu(const unsigned short* __restrict__ y1,
                                               const float* __restrict__ g,
                                               const float* __restrict__ be,
                                               unsigned short* __restrict__ Gonly) {
    __shared__ float2 red[2][2];
    int t = threadIdx.x;
    int rhalf = t >> 7, l = t & 127, wid = (t >> 6) & 1;
    int m = blockIdx.x * 2 + rhalf;
    bf16x8 u = *(const bf16x8*)(y1 + (size_t)m * HIDN + l * 8);
    float v[8];
    float s = 0.f, ss = 0.f;
#pragma unroll
    for (int j = 0; j < 8; j++) {
        v[j] = bf2f((unsigned short)u[j]);
        s += v[j]; ss += v[j] * v[j];
    }
    for (int off = 32; off > 0; off >>= 1) {
        s  += __shfl_down(s, off, 64);
        ss += __shfl_down(ss, off, 64);
    }
    if ((t & 63) == 0) red[rhalf][wid] = make_float2(s, ss);
    __syncthreads();
    float sT  = red[rhalf][0].x + red[rhalf][1].x;
    float ssT = red[rhalf][0].y + red[rhalf][1].y;
    float mu = sT * (1.f / HIDN);
    float var = ssT * (1.f / HIDN) - mu * mu;
    float rs = rsqrtf(var + 1e-5f);
    float4 gA = *(const float4*)(g + l * 8),  gB = *(const float4*)(g + l * 8 + 4);
    float4 bA = *(const float4*)(be + l * 8), bB = *(const float4*)(be + l * 8 + 4);
    float gv[8] = { gA.x, gA.y, gA.z, gA.w, gB.x, gB.y, gB.z, gB.w };
    float bv[8] = { bA.x, bA.y, bA.z, bA.w, bB.x, bB.y, bB.z, bB.w };
    bf16x8 p1;
#pragma unroll
    for (int j = 0; j < 8; j++) {
        float xn = (v[j] - mu) * rs * gv[j] + bv[j];
        float gl = xn * 0.5f * (1.f + erff(xn * 0.70710678118654752f));
        p1[j] = (short)f2bf(gl);
    }
    *(bf16x8*)(Gonly + (size_t)m * HIDN + l * 8) = p1;
}

// ---------------- kan2_gemm: y2 = sum_c g*C1 + g^2*C2 + g^3*C3, powers in-register.
// A = Gonly (M x 1024), B = W2T (N x 3072, planes at +0/+1024/+2048). BK=64, 16 steps.
__global__ __launch_bounds__(256) void kan2_gemm(const unsigned short* __restrict__ G,
                                                 const unsigned short* __restrict__ W2T,
                                                 const float* __restrict__ beff,
                                                 unsigned short* __restrict__ Y) {
    __shared__ unsigned short smem[128 * 64 * 4];  // As (16KB) + Bs 3 planes (48KB) = 64KB
    unsigned short* As = smem;
    unsigned short* Bs = smem + 128 * 64;
    int t = threadIdx.x, lane = t & 63, wave = t >> 6;
    int m0 = blockIdx.x * 128, n0 = blockIdx.y * 128;
    int srow = lane >> 3, sgcc = (lane & 7) ^ srow;
    const unsigned short* Ab = G + (size_t)m0 * HIDN;
    const unsigned short* Bb = W2T + (size_t)n0 * KTOT;

    f32x16 acc[2][2] = {};
    int wr = (wave >> 1) * 64, wc = (wave & 1) * 64;
    int row32 = lane & 31, half = lane >> 5;

    for (int c0 = 0; c0 < HIDN; c0 += 64) {
#pragma unroll
        for (int j = 0; j < 4; j++) {
            int rgrp = wave * 32 + j * 8;
            gload_lds16(Ab + ((size_t)(rgrp + srow) * HIDN + c0 + sgcc * 8), As + rgrp * 64);
#pragma unroll
            for (int p = 0; p < 3; p++)
                gload_lds16(Bb + ((size_t)(rgrp + srow) * KTOT + p * HIDN + c0 + sgcc * 8),
                            Bs + p * 128 * 64 + rgrp * 64);
        }
        __syncthreads();
#pragma unroll
        for (int ks = 0; ks < 4; ks++) {
            int cidx = ks * 2 + half;
            bf16x8 af[2], af2[2], af3[2];
#pragma unroll
            for (int mt = 0; mt < 2; mt++) {
                int r = wr + mt * 32 + row32;
                af[mt] = *(const bf16x8*)(As + r * 64 + ((cidx ^ (r & 7)) << 3));
                powfrags(af[mt], af2[mt], af3[mt]);
            }
#pragma unroll
            for (int nt = 0; nt < 2; nt++) {
                int c = wc + nt * 32 + row32;
                int boff = c * 64 + ((cidx ^ (c & 7)) << 3);
                bf16x8 b1 = *(const bf16x8*)(Bs + boff);
                bf16x8 b2 = *(const bf16x8*)(Bs + 128 * 64 + boff);
                bf16x8 b3 = *(const bf16x8*)(Bs + 2 * 128 * 64 + boff);
#pragma unroll
                for (int mt = 0; mt < 2; mt++) {
                    acc[mt][nt] = __builtin_amdgcn_mfma_f32_32x32x16_bf16(af[mt],  b1, acc[mt][nt], 0, 0, 0);
                    acc[mt][nt] = __builtin_amdgcn_mfma_f32_32x32x16_bf16(af2[mt], b2, acc[mt][nt], 0, 0, 0);
                    acc[mt][nt] = __builtin_amdgcn_mfma_f32_32x32x16_bf16(af3[mt], b3, acc[mt][nt], 0, 0, 0);
                }
            }
        }
        __syncthreads();
    }
#pragma unroll
    for (int nt = 0; nt < 2; nt++) {
        int oc = n0 + wc + nt * 32 + row32;
        float bo = beff[oc];
#pragma unroll
        for (int mt = 0; mt < 2; mt++) {
#pragma unroll
            for (int reg = 0; reg < 16; reg++) {
                int rl = (reg & 3) + 8 * (reg >> 2) + 4 * half;
                int mr = m0 + wr + mt * 32 + rl;
                Y[(size_t)mr * OUTN + oc] = f2bf(acc[mt][nt][reg] + bo);
            }
        }
    }
}

// ---------------- Stage A: LN(512) per row (bf16 y2) + partial mean over L-chunk
__global__ __launch_bounds__(256) void ln_pool_partial(const unsigned short* __restrict__ y2,
                                                       const float* __restrict__ g,
                                                       const float* __restrict__ be,
                                                       float* __restrict__ partial) {
    __shared__ float part[4][OUTN];
    int t = threadIdx.x, lane = t & 63, wave = t >> 6;
    int b = blockIdx.x, chunk = blockIdx.y;
    int mbase = b * LEN + chunk * LROWS;

    float4 gA = *(const float4*)(g + 8 * lane),  gB = *(const float4*)(g + 8 * lane + 4);
    float4 bA = *(const float4*)(be + 8 * lane), bB = *(const float4*)(be + 8 * lane + 4);
    float gv[8] = { gA.x, gA.y, gA.z, gA.w, gB.x, gB.y, gB.z, gB.w };
    float bv[8] = { bA.x, bA.y, bA.z, bA.w, bB.x, bB.y, bB.z, bB.w };

    float acc[8] = {0.f, 0.f, 0.f, 0.f, 0.f, 0.f, 0.f, 0.f};
    for (int rr = wave; rr < LROWS; rr += 4) {
        bf16x8 u = *(const bf16x8*)(y2 + (size_t)(mbase + rr) * OUTN + 8 * lane);
        float v[8];
        float s = 0.f, ss = 0.f;
#pragma unroll
        for (int j = 0; j < 8; j++) {
            v[j] = bf2f((unsigned short)u[j]);
            s += v[j]; ss += v[j] * v[j];
        }
        for (int off = 32; off > 0; off >>= 1) {
            s  += __shfl_down(s, off, 64);
            ss += __shfl_down(ss, off, 64);
        }
        s  = __shfl(s, 0, 64);
        ss = __shfl(ss, 0, 64);
        float mu = s * (1.f / OUTN);
        float var = ss * (1.f / OUTN) - mu * mu;
        float rs = rsqrtf(var + 1e-5f);
#pragma unroll
        for (int j = 0; j < 8; j++)
            acc[j] += (v[j] - mu) * rs * gv[j] + bv[j];
    }
    *(float4*)(&part[wave][8 * lane])     = *(float4*)(&acc[0]);
    *(float4*)(&part[wave][8 * lane + 4]) = *(float4*)(&acc[4]);
    __syncthreads();
    float p0 = part[0][2*t] + part[1][2*t] + part[2][2*t] + part[3][2*t];
    float p1 = part[0][2*t+1] + part[1][2*t+1] + part[2][2*t+1] + part[3][2*t+1];
    float* dst = partial + ((size_t)b * LCHUNKS + chunk) * OUTN;
    *(float2*)(dst + 2 * t) = make_float2(p0, p1);
}

// ---------------- Stage B: reduce 32 chunk-partials -> out[b][o]
__global__ __launch_bounds__(256) void pool_reduce(const float* __restrict__ partial,
                                                   float* __restrict__ out) {
    int b = blockIdx.x, t = threadIdx.x;
    const float* src = partial + (size_t)b * LCHUNKS * OUTN;
    float s0 = 0.f, s1 = 0.f;
    for (int c = 0; c < LCHUNKS; c++) {
        float2 v = *(const float2*)(src + (size_t)c * OUTN + 2 * t);
        s0 += v.x; s1 += v.y;
    }
    *(float2*)(out + (size_t)b * OUTN + 2 * t) = make_float2(s0 * (1.f / LEN), s1 * (1.f / LEN));
}

extern "C" void kernel_launch(void* const* d_in, const int* in_sizes, int n_in,
                              void* d_out, int out_size, void* d_ws, size_t ws_size,
                              hipStream_t stream) {
    const float* x       = (const float*)d_in[0];
    const float* Win     = (const float*)d_in[1];
    const float* bin     = (const float*)d_in[2];
    const float* coeffs1 = (const float*)d_in[3];
    const float* bias1   = (const float*)d_in[4];
    const float* g1      = (const float*)d_in[5];
    const float* beta1   = (const float*)d_in[6];
    const float* coeffs2 = (const float*)d_in[7];
    const float* bias2   = (const float*)d_in[8];
    const float* g2      = (const float*)d_in[9];
    const float* beta2   = (const float*)d_in[10];
    float* out = (float*)d_out;

    char* ws = (char*)d_ws;
    // A1 (M x 2112 bf16) dead after GEMM1; Gonly (M x 1024 bf16) aliases it.
    unsigned short* A1    = (unsigned short*)ws;
    unsigned short* Gonly = (unsigned short*)ws;
    char* p1 = ws + (size_t)MTOT * KTOT * 2;
    unsigned short* y1   = (unsigned short*)p1;                         // 33,554,432 B
    unsigned short* y2   = (unsigned short*)p1;                         // alias (16 MB)
    char* p2 = p1 + (size_t)MTOT * HIDN * 2;
    unsigned short* W1T  = (unsigned short*)p2;                         // 1024*2112*2
    char* p3 = p2 + (size_t)HIDN * KT1 * 2;
    unsigned short* W2T  = (unsigned short*)p3;                         // 512*3072*2
    char* p4 = p3 + (size_t)OUTN * KTOT * 2;
    float* b1e = (float*)p4;
    float* b2e = (float*)(p4 + HIDN * sizeof(float));
    char* p5 = p4 + (HIDN + OUTN) * sizeof(float);
    unsigned short* xT   = (unsigned short*)p5;                         // 2,097,152 B
    char* p6 = p5 + (size_t)MTOT * CIN * 2;
    unsigned short* WinT = (unsigned short*)p6;                         // 131,072 B
    float* partial = (float*)W1T;    // alias: W1T dead after GEMM1 (needs 1 MB)

    prep_all<<<1808, 256, 0, stream>>>(coeffs1, bias1, coeffs2, bias2, x, Win,
                                       W1T, b1e, W2T, b2e, xT, WinT);
    proj_mfma<<<dim3(MTOT / 128, HIDN / 128), 256, 0, stream>>>(xT, WinT, bin, A1,
                                                                coeffs1, W1T, b1e);
    mfma_gemm<HIDN, KT1, true><<<dim3(MTOT / 128, HIDN / 128), 256, 0, stream>>>(A1, W1T, b1e, y1);
    ln_gelu<<<MTOT / 2, 256, 0, stream>>>(y1, g1, beta1, Gonly);
    kan2_gemm<<<dim3(MTOT / 128, OUTN / 128), 256, 0, stream>>>(Gonly, W2T, b2e, y2);
    ln_pool_partial<<<dim3(Bsz, LCHUNKS), 256, 0, stream>>>(y2, g2, beta2, partial);
    pool_reduce<<<Bsz, 256, 0, stream>>>(partial, out);
}

// Round 9
// 286.816 us; speedup vs baseline: 1.6948x; 1.0004x over previous
//
#include <hip/hip_runtime.h>
#include <hip/hip_bf16.h>
#include <math.h>

#define Bsz  16
#define CIN  64
#define LEN  1024
#define HIDN 1024
#define OUTN 512
#define MTOT (Bsz*LEN)   // 16384
#define KTOT (3*HIDN)    // 3072 (W2T plane stride basis)
#define KT1H (2*HIDN)    // 2048 (W1T: [C2 | C3])
#define LCHUNKS 32
#define LROWS   (LEN/LCHUNKS)  // 32 rows per block

typedef __attribute__((ext_vector_type(8))) short bf16x8;
typedef __attribute__((ext_vector_type(16))) float f32x16;

__device__ __forceinline__ unsigned short f2bf(float x) {
    union { float f; unsigned int u; } v; v.f = x;
    unsigned int r = v.u + 0x7fff + ((v.u >> 16) & 1);   // RNE
    return (unsigned short)(r >> 16);
}
__device__ __forceinline__ float bf2f(unsigned short u) {
    union { unsigned int u; float f; } v; v.u = ((unsigned int)u) << 16;
    return v.f;
}
__device__ __forceinline__ void gload_lds16(const void* g, void* l) {
    __builtin_amdgcn_global_load_lds((const __attribute__((address_space(1))) void*)g,
                                     (__attribute__((address_space(3))) void*)l, 16, 0, 0);
}
// a (bf16x8) -> a2=a^2, a3=a^3 via packed RNE converts
__device__ __forceinline__ void powfrags(const bf16x8& a, bf16x8& a2, bf16x8& a3) {
#pragma unroll
    for (int j = 0; j < 4; j++) {
        float f0 = bf2f((unsigned short)a[2 * j]);
        float f1 = bf2f((unsigned short)a[2 * j + 1]);
        float s0 = f0 * f0, s1 = f1 * f1;
        __hip_bfloat162 p2 = __float22bfloat162_rn(float2{ s0, s1 });
        __hip_bfloat162 p3 = __float22bfloat162_rn(float2{ s0 * f0, s1 * f1 });
        ((unsigned int*)&a2)[j] = *(unsigned int*)&p2;
        ((unsigned int*)&a3)[j] = *(unsigned int*)&p3;
    }
}

// ---------------- prep_all:
//  [0,1024)      coeffs1 row o -> W1T[o] = [C2 | C3] (stride KT1H), b1e = bias1 + sum C0
//  [1024,1536)   coeffs2 row o -> W2T[o] = [C1|C2|C3] (stride KTOT), b2e
//  [1536,1792)   x (B,C,L) 64x64 transpose -> xT[b][l][c] bf16
//  [1792,1808)   Win (C,H) 64x64 transpose -> WinT[h][c] bf16
__global__ __launch_bounds__(256) void prep_all(const float* __restrict__ coeffs1,
                                                const float* __restrict__ bias1,
                                                const float* __restrict__ coeffs2,
                                                const float* __restrict__ bias2,
                                                const float* __restrict__ x,
                                                const float* __restrict__ Win,
                                                unsigned short* __restrict__ W1T,
                                                float* __restrict__ b1e,
                                                unsigned short* __restrict__ W2T,
                                                float* __restrict__ b2e,
                                                unsigned short* __restrict__ xT,
                                                unsigned short* __restrict__ WinT) {
    __shared__ float sm[64 * 65];
    int bid = blockIdx.x, t = threadIdx.x;
    if (bid < 1024) {
        int o = bid;
        float s = 0.f;
        unsigned short* wrow = W1T + (size_t)o * KT1H;
        for (int c = t; c < HIDN; c += 256) {
            float4 v = *(const float4*)(coeffs1 + ((size_t)o * HIDN + c) * 4);
            s += v.x;                       // order-0 -> bias
            wrow[c]        = f2bf(v.z);     // C2 plane
            wrow[HIDN + c] = f2bf(v.w);     // C3 plane  (C1 handled via wc1_kernel)
        }
        for (int off = 32; off > 0; off >>= 1) s += __shfl_down(s, off, 64);
        if ((t & 63) == 0) sm[t >> 6] = s;
        __syncthreads();
        if (t == 0) b1e[o] = bias1[o] + sm[0] + sm[1] + sm[2] + sm[3];
    } else if (bid < 1536) {
        int o = bid - 1024;
        float s = 0.f;
        unsigned short* wrow = W2T + (size_t)o * KTOT;
        for (int c = t; c < HIDN; c += 256) {
            float4 v = *(const float4*)(coeffs2 + ((size_t)o * HIDN + c) * 4);
            s += v.x;
            wrow[c]            = f2bf(v.y);
            wrow[HIDN + c]     = f2bf(v.z);
            wrow[2 * HIDN + c] = f2bf(v.w);
        }
        for (int off = 32; off > 0; off >>= 1) s += __shfl_down(s, off, 64);
        if ((t & 63) == 0) sm[t >> 6] = s;
        __syncthreads();
        if (t == 0) b2e[o] = bias2[o] + sm[0] + sm[1] + sm[2] + sm[3];
    } else {
        const float* src; unsigned short* dstbase; size_t src_rstride;
        int c0;
        if (bid < 1792) {
            int tile = bid - 1536; int b = tile >> 4; c0 = (tile & 15) * 64;
            src = x + (size_t)b * CIN * LEN;  src_rstride = LEN;
            dstbase = xT + ((size_t)b * LEN + c0) * CIN;
        } else {
            int tile = bid - 1792; c0 = tile * 64;
            src = Win; src_rstride = HIDN;
            dstbase = WinT + (size_t)c0 * CIN;
        }
#pragma unroll
        for (int it = 0; it < 4; it++) {
            int idx = t + it * 256;
            int c = idx >> 4, q = idx & 15;
            float4 v = *(const float4*)(src + (size_t)c * src_rstride + c0 + q * 4);
            sm[c * 65 + q * 4 + 0] = v.x;
            sm[c * 65 + q * 4 + 1] = v.y;
            sm[c * 65 + q * 4 + 2] = v.z;
            sm[c * 65 + q * 4 + 3] = v.w;
        }
        __syncthreads();
        int ll = t >> 2, cg = (t & 3) * 16;
        unsigned short* dst = dstbase + (size_t)ll * CIN + cg;
#pragma unroll
        for (int j = 0; j < 4; j++) {
            int c = cg + j * 4;
            ushort4 w = { f2bf(sm[(c + 0) * 65 + ll]), f2bf(sm[(c + 1) * 65 + ll]),
                          f2bf(sm[(c + 2) * 65 + ll]), f2bf(sm[(c + 3) * 65 + ll]) };
            *(ushort4*)(dst + j * 4) = w;
        }
    }
}

// ---------------- wc1: WC1[o][cin] = sum_c Win[cin][c]*C1[o][c];  b1e[o] += bin . C1[o]
__global__ __launch_bounds__(256) void wc1_kernel(const float* __restrict__ coeffs1,
                                                  const unsigned short* __restrict__ WinT,
                                                  const float* __restrict__ bin,
                                                  unsigned short* __restrict__ WC1,
                                                  float* __restrict__ b1e) {
    __shared__ float c1s[HIDN];
    __shared__ float part[4][64];
    __shared__ float pbred[4];
    int o = blockIdx.x, t = threadIdx.x, lane = t & 63, wave = t >> 6;
    for (int c = t; c < HIDN; c += 256)
        c1s[c] = coeffs1[((size_t)o * HIDN + c) * 4 + 1];
    __syncthreads();
    float acc = 0.f;
    int cbase = wave * 256;
    for (int c = cbase; c < cbase + 256; c++)
        acc += bf2f(WinT[c * CIN + lane]) * c1s[c];
    part[wave][lane] = acc;
    float pb = 0.f;
    for (int c = t; c < HIDN; c += 256) pb += bin[c] * c1s[c];
    for (int off = 32; off > 0; off >>= 1) pb += __shfl_down(pb, off, 64);
    if (lane == 0) pbred[wave] = pb;
    __syncthreads();
    if (t < 64) {
        float v = part[0][t] + part[1][t] + part[2][t] + part[3][t];
        WC1[(size_t)o * CIN + t] = f2bf(v);
    }
    if (t == 0) b1e[o] += pbred[0] + pbred[1] + pbred[2] + pbred[3];
}

// ---------------- proj_mfma: h = xT @ WinT^T + bin (K=64); write ONLY h (bf16)
__global__ __launch_bounds__(256) void proj_mfma(const unsigned short* __restrict__ xT,
                                                 const unsigned short* __restrict__ WinT,
                                                 const float* __restrict__ bin,
                                                 unsigned short* __restrict__ Hout) {
    __shared__ unsigned short smem[2 * 128 * 64];   // staging; reused as 128x128 ht
    unsigned short* As = smem;
    unsigned short* Bs = smem + 128 * 64;
    unsigned short* ht = smem;
    int t = threadIdx.x, lane = t & 63, wave = t >> 6;
    int m0 = blockIdx.x * 128, n0 = blockIdx.y * 128;
    int srow = lane >> 3, sgcc = (lane & 7) ^ srow;
    const unsigned short* Ab = xT + (size_t)m0 * CIN;
    const unsigned short* Bb = WinT + (size_t)n0 * CIN;

    f32x16 acc[2][2] = {};
    int wr = (wave >> 1) * 64, wc = (wave & 1) * 64;
    int row32 = lane & 31, half = lane >> 5;

#pragma unroll
    for (int j = 0; j < 4; j++) {
        int rgrp = wave * 32 + j * 8;
        gload_lds16(Ab + (size_t)(rgrp + srow) * CIN + sgcc * 8, As + rgrp * 64);
        gload_lds16(Bb + (size_t)(rgrp + srow) * CIN + sgcc * 8, Bs + rgrp * 64);
    }
    __syncthreads();
#pragma unroll
    for (int ks = 0; ks < 4; ks++) {
        int cidx = ks * 2 + half;
        bf16x8 af[2], bf[2];
#pragma unroll
        for (int mt = 0; mt < 2; mt++) {
            int r = wr + mt * 32 + row32;
            af[mt] = *(const bf16x8*)(As + r * 64 + ((cidx ^ (r & 7)) << 3));
        }
#pragma unroll
        for (int nt = 0; nt < 2; nt++) {
            int c = wc + nt * 32 + row32;
            bf[nt] = *(const bf16x8*)(Bs + c * 64 + ((cidx ^ (c & 7)) << 3));
        }
#pragma unroll
        for (int mt = 0; mt < 2; mt++)
#pragma unroll
            for (int nt = 0; nt < 2; nt++)
                acc[mt][nt] = __builtin_amdgcn_mfma_f32_32x32x16_bf16(af[mt], bf[nt], acc[mt][nt], 0, 0, 0);
    }
    __syncthreads();   // safe to reuse smem
#pragma unroll
    for (int nt = 0; nt < 2; nt++) {
        int ocl = wc + nt * 32 + row32;
        float bo = bin[n0 + ocl];
#pragma unroll
        for (int mt = 0; mt < 2; mt++) {
#pragma unroll
            for (int reg = 0; reg < 16; reg++) {
                int rl = wr + mt * 32 + (reg & 3) + 8 * (reg >> 2) + 4 * half;
                ht[rl * 128 + ocl] = f2bf(acc[mt][nt][reg] + bo);
            }
        }
    }
    __syncthreads();
    // h plane, 16B stores
#pragma unroll
    for (int p = 0; p < 8; p++) {
        int r = p * 16 + (t >> 4);
        int c = (t & 15) * 8;
        bf16x8 hv = *(const bf16x8*)(ht + r * 128 + c);
        *(bf16x8*)(Hout + (size_t)(m0 + r) * HIDN + n0 + c) = hv;
    }
}

// ---------------- kan1_gemm: y1 = h^2@C2^T + h^3@C3^T + x@WC1^T + b1e; powers in-register.
// A = H (M x 1024); B = W1T (N x 2048: [C2|C3]); tail: xT (M x 64) @ WC1 (N x 64).
__global__ __launch_bounds__(256) void kan1_gemm(const unsigned short* __restrict__ H,
                                                 const unsigned short* __restrict__ xT,
                                                 const unsigned short* __restrict__ W1T,
                                                 const unsigned short* __restrict__ WC1,
                                                 const float* __restrict__ beff,
                                                 unsigned short* __restrict__ Y) {
    __shared__ unsigned short smem[128 * 64 * 3];  // As 16KB + Bs 2 planes 32KB = 48KB
    unsigned short* As = smem;
    unsigned short* Bs = smem + 128 * 64;
    int t = threadIdx.x, lane = t & 63, wave = t >> 6;
    int m0 = blockIdx.x * 128, n0 = blockIdx.y * 128;
    int srow = lane >> 3, sgcc = (lane & 7) ^ srow;
    const unsigned short* Ab = H + (size_t)m0 * HIDN;
    const unsigned short* Bb = W1T + (size_t)n0 * KT1H;

    f32x16 acc[2][2] = {};
    int wr = (wave >> 1) * 64, wc = (wave & 1) * 64;
    int row32 = lane & 31, half = lane >> 5;

    for (int c0 = 0; c0 < HIDN; c0 += 64) {
#pragma unroll
        for (int j = 0; j < 4; j++) {
            int rgrp = wave * 32 + j * 8;
            gload_lds16(Ab + ((size_t)(rgrp + srow) * HIDN + c0 + sgcc * 8), As + rgrp * 64);
#pragma unroll
            for (int p = 0; p < 2; p++)
                gload_lds16(Bb + ((size_t)(rgrp + srow) * KT1H + p * HIDN + c0 + sgcc * 8),
                            Bs + p * 128 * 64 + rgrp * 64);
        }
        __syncthreads();
#pragma unroll
        for (int ks = 0; ks < 4; ks++) {
            int cidx = ks * 2 + half;
            bf16x8 af2[2], af3[2];
#pragma unroll
            for (int mt = 0; mt < 2; mt++) {
                int r = wr + mt * 32 + row32;
                bf16x8 af = *(const bf16x8*)(As + r * 64 + ((cidx ^ (r & 7)) << 3));
                powfrags(af, af2[mt], af3[mt]);
            }
#pragma unroll
            for (int nt = 0; nt < 2; nt++) {
                int c = wc + nt * 32 + row32;
                int boff = c * 64 + ((cidx ^ (c & 7)) << 3);
                bf16x8 b2 = *(const bf16x8*)(Bs + boff);
                bf16x8 b3 = *(const bf16x8*)(Bs + 128 * 64 + boff);
#pragma unroll
                for (int mt = 0; mt < 2; mt++) {
                    acc[mt][nt] = __builtin_amdgcn_mfma_f32_32x32x16_bf16(af2[mt], b2, acc[mt][nt], 0, 0, 0);
                    acc[mt][nt] = __builtin_amdgcn_mfma_f32_32x32x16_bf16(af3[mt], b3, acc[mt][nt], 0, 0, 0);
                }
            }
        }
        __syncthreads();
    }
    // linear x-tail: K=64
#pragma unroll
    for (int j = 0; j < 4; j++) {
        int rgrp = wave * 32 + j * 8;
        gload_lds16(xT  + (size_t)(m0 + rgrp + srow) * CIN + sgcc * 8, As + rgrp * 64);
        gload_lds16(WC1 + (size_t)(n0 + rgrp + srow) * CIN + sgcc * 8, Bs + rgrp * 64);
    }
    __syncthreads();
#pragma unroll
    for (int ks = 0; ks < 4; ks++) {
        int cidx = ks * 2 + half;
        bf16x8 af[2], bf[2];
#pragma unroll
        for (int mt = 0; mt < 2; mt++) {
            int r = wr + mt * 32 + row32;
            af[mt] = *(const bf16x8*)(As + r * 64 + ((cidx ^ (r & 7)) << 3));
        }
#pragma unroll
        for (int nt = 0; nt < 2; nt++) {
            int c = wc + nt * 32 + row32;
            bf[nt] = *(const bf16x8*)(Bs + c * 64 + ((cidx ^ (c & 7)) << 3));
        }
#pragma unroll
        for (int mt = 0; mt < 2; mt++)
#pragma unroll
            for (int nt = 0; nt < 2; nt++)
                acc[mt][nt] = __builtin_amdgcn_mfma_f32_32x32x16_bf16(af[mt], bf[nt], acc[mt][nt], 0, 0, 0);
    }
#pragma unroll
    for (int nt = 0; nt < 2; nt++) {
        int oc = n0 + wc + nt * 32 + row32;
        float bo = beff[oc];
#pragma unroll
        for (int mt = 0; mt < 2; mt++) {
#pragma unroll
            for (int reg = 0; reg < 16; reg++) {
                int rl = (reg & 3) + 8 * (reg >> 2) + 4 * half;
                int mr = m0 + wr + mt * 32 + rl;
                Y[(size_t)mr * HIDN + oc] = f2bf(acc[mt][nt][reg] + bo);
            }
        }
    }
}

// ---------------- LN(1024) + exact GELU, emit ONLY g (bf16); 2 rows/block
__global__ __launch_bounds__(256) void ln_gelu(const unsigned short* __restrict__ y1,
                                               const float* __restrict__ g,
                                               const float* __restrict__ be,
                                               unsigned short* __restrict__ Gonly) {
    __shared__ float2 red[2][2];
    int t = threadIdx.x;
    int rhalf = t >> 7, l = t & 127, wid = (t >> 6) & 1;
    int m = blockIdx.x * 2 + rhalf;
    bf16x8 u = *(const bf16x8*)(y1 + (size_t)m * HIDN + l * 8);
    float v[8];
    float s = 0.f, ss = 0.f;
#pragma unroll
    for (int j = 0; j < 8; j++) {
        v[j] = bf2f((unsigned short)u[j]);
        s += v[j]; ss += v[j] * v[j];
    }
    for (int off = 32; off > 0; off >>= 1) {
        s  += __shfl_down(s, off, 64);
        ss += __shfl_down(ss, off, 64);
    }
    if ((t & 63) == 0) red[rhalf][wid] = make_float2(s, ss);
    __syncthreads();
    float sT  = red[rhalf][0].x + red[rhalf][1].x;
    float ssT = red[rhalf][0].y + red[rhalf][1].y;
    float mu = sT * (1.f / HIDN);
    float var = ssT * (1.f / HIDN) - mu * mu;
    float rs = rsqrtf(var + 1e-5f);
    float4 gA = *(const float4*)(g + l * 8),  gB = *(const float4*)(g + l * 8 + 4);
    float4 bA = *(const float4*)(be + l * 8), bB = *(const float4*)(be + l * 8 + 4);
    float gv[8] = { gA.x, gA.y, gA.z, gA.w, gB.x, gB.y, gB.z, gB.w };
    float bv[8] = { bA.x, bA.y, bA.z, bA.w, bB.x, bB.y, bB.z, bB.w };
    bf16x8 p1;
#pragma unroll
    for (int j = 0; j < 8; j++) {
        float xn = (v[j] - mu) * rs * gv[j] + bv[j];
        float gl = xn * 0.5f * (1.f + erff(xn * 0.70710678118654752f));
        p1[j] = (short)f2bf(gl);
    }
    *(bf16x8*)(Gonly + (size_t)m * HIDN + l * 8) = p1;
}

// ---------------- kan2_gemm: y2 = g@C1 + g^2@C2 + g^3@C3 + b2e, powers in-register.
__global__ __launch_bounds__(256) void kan2_gemm(const unsigned short* __restrict__ G,
                                                 const unsigned short* __restrict__ W2T,
                                                 const float* __restrict__ beff,
                                                 unsigned short* __restrict__ Y) {
    __shared__ unsigned short smem[128 * 64 * 4];  // As 16KB + Bs 3 planes 48KB
    unsigned short* As = smem;
    unsigned short* Bs = smem + 128 * 64;
    int t = threadIdx.x, lane = t & 63, wave = t >> 6;
    int m0 = blockIdx.x * 128, n0 = blockIdx.y * 128;
    int srow = lane >> 3, sgcc = (lane & 7) ^ srow;
    const unsigned short* Ab = G + (size_t)m0 * HIDN;
    const unsigned short* Bb = W2T + (size_t)n0 * KTOT;

    f32x16 acc[2][2] = {};
    int wr = (wave >> 1) * 64, wc = (wave & 1) * 64;
    int row32 = lane & 31, half = lane >> 5;

    for (int c0 = 0; c0 < HIDN; c0 += 64) {
#pragma unroll
        for (int j = 0; j < 4; j++) {
            int rgrp = wave * 32 + j * 8;
            gload_lds16(Ab + ((size_t)(rgrp + srow) * HIDN + c0 + sgcc * 8), As + rgrp * 64);
#pragma unroll
            for (int p = 0; p < 3; p++)
                gload_lds16(Bb + ((size_t)(rgrp + srow) * KTOT + p * HIDN + c0 + sgcc * 8),
                            Bs + p * 128 * 64 + rgrp * 64);
        }
        __syncthreads();
#pragma unroll
        for (int ks = 0; ks < 4; ks++) {
            int cidx = ks * 2 + half;
            bf16x8 af[2], af2[2], af3[2];
#pragma unroll
            for (int mt = 0; mt < 2; mt++) {
                int r = wr + mt * 32 + row32;
                af[mt] = *(const bf16x8*)(As + r * 64 + ((cidx ^ (r & 7)) << 3));
                powfrags(af[mt], af2[mt], af3[mt]);
            }
#pragma unroll
            for (int nt = 0; nt < 2; nt++) {
                int c = wc + nt * 32 + row32;
                int boff = c * 64 + ((cidx ^ (c & 7)) << 3);
                bf16x8 b1 = *(const bf16x8*)(Bs + boff);
                bf16x8 b2 = *(const bf16x8*)(Bs + 128 * 64 + boff);
                bf16x8 b3 = *(const bf16x8*)(Bs + 2 * 128 * 64 + boff);
#pragma unroll
                for (int mt = 0; mt < 2; mt++) {
                    acc[mt][nt] = __builtin_amdgcn_mfma_f32_32x32x16_bf16(af[mt],  b1, acc[mt][nt], 0, 0, 0);
                    acc[mt][nt] = __builtin_amdgcn_mfma_f32_32x32x16_bf16(af2[mt], b2, acc[mt][nt], 0, 0, 0);
                    acc[mt][nt] = __builtin_amdgcn_mfma_f32_32x32x16_bf16(af3[mt], b3, acc[mt][nt], 0, 0, 0);
                }
            }
        }
        __syncthreads();
    }
#pragma unroll
    for (int nt = 0; nt < 2; nt++) {
        int oc = n0 + wc + nt * 32 + row32;
        float bo = beff[oc];
#pragma unroll
        for (int mt = 0; mt < 2; mt++) {
#pragma unroll
            for (int reg = 0; reg < 16; reg++) {
                int rl = (reg & 3) + 8 * (reg >> 2) + 4 * half;
                int mr = m0 + wr + mt * 32 + rl;
                Y[(size_t)mr * OUTN + oc] = f2bf(acc[mt][nt][reg] + bo);
            }
        }
    }
}

// ---------------- Stage A: LN(512) per row (bf16 y2) + partial mean over L-chunk
__global__ __launch_bounds__(256) void ln_pool_partial(const unsigned short* __restrict__ y2,
                                                       const float* __restrict__ g,
                                                       const float* __restrict__ be,
                                                       float* __restrict__ partial) {
    __shared__ float part[4][OUTN];
    int t = threadIdx.x, lane = t & 63, wave = t >> 6;
    int b = blockIdx.x, chunk = blockIdx.y;
    int mbase = b * LEN + chunk * LROWS;

    float4 gA = *(const float4*)(g + 8 * lane),  gB = *(const float4*)(g + 8 * lane + 4);
    float4 bA = *(const float4*)(be + 8 * lane), bB = *(const float4*)(be + 8 * lane + 4);
    float gv[8] = { gA.x, gA.y, gA.z, gA.w, gB.x, gB.y, gB.z, gB.w };
    float bv[8] = { bA.x, bA.y, bA.z, bA.w, bB.x, bB.y, bB.z, bB.w };

    float acc[8] = {0.f, 0.f, 0.f, 0.f, 0.f, 0.f, 0.f, 0.f};
    for (int rr = wave; rr < LROWS; rr += 4) {
        bf16x8 u = *(const bf16x8*)(y2 + (size_t)(mbase + rr) * OUTN + 8 * lane);
        float v[8];
        float s = 0.f, ss = 0.f;
#pragma unroll
        for (int j = 0; j < 8; j++) {
            v[j] = bf2f((unsigned short)u[j]);
            s += v[j]; ss += v[j] * v[j];
        }
        for (int off = 32; off > 0; off >>= 1) {
            s  += __shfl_down(s, off, 64);
            ss += __shfl_down(ss, off, 64);
        }
        s  = __shfl(s, 0, 64);
        ss = __shfl(ss, 0, 64);
        float mu = s * (1.f / OUTN);
        float var = ss * (1.f / OUTN) - mu * mu;
        float rs = rsqrtf(var + 1e-5f);
#pragma unroll
        for (int j = 0; j < 8; j++)
            acc[j] += (v[j] - mu) * rs * gv[j] + bv[j];
    }
    *(float4*)(&part[wave][8 * lane])     = *(float4*)(&acc[0]);
    *(float4*)(&part[wave][8 * lane + 4]) = *(float4*)(&acc[4]);
    __syncthreads();
    float p0 = part[0][2*t] + part[1][2*t] + part[2][2*t] + part[3][2*t];
    float p1 = part[0][2*t+1] + part[1][2*t+1] + part[2][2*t+1] + part[3][2*t+1];
    float* dst = partial + ((size_t)b * LCHUNKS + chunk) * OUTN;
    *(float2*)(dst + 2 * t) = make_float2(p0, p1);
}

// ---------------- Stage B: reduce 32 chunk-partials -> out[b][o]
__global__ __launch_bounds__(256) void pool_reduce(const float* __restrict__ partial,
                                                   float* __restrict__ out) {
    int b = blockIdx.x, t = threadIdx.x;
    const float* src = partial + (size_t)b * LCHUNKS * OUTN;
    float s0 = 0.f, s1 = 0.f;
    for (int c = 0; c < LCHUNKS; c++) {
        float2 v = *(const float2*)(src + (size_t)c * OUTN + 2 * t);
        s0 += v.x; s1 += v.y;
    }
    *(float2*)(out + (size_t)b * OUTN + 2 * t) = make_float2(s0 * (1.f / LEN), s1 * (1.f / LEN));
}

extern "C" void kernel_launch(void* const* d_in, const int* in_sizes, int n_in,
                              void* d_out, int out_size, void* d_ws, size_t ws_size,
                              hipStream_t stream) {
    const float* x       = (const float*)d_in[0];
    const float* Win     = (const float*)d_in[1];
    const float* bin     = (const float*)d_in[2];
    const float* coeffs1 = (const float*)d_in[3];
    const float* bias1   = (const float*)d_in[4];
    const float* g1      = (const float*)d_in[5];
    const float* beta1   = (const float*)d_in[6];
    const float* coeffs2 = (const float*)d_in[7];
    const float* bias2   = (const float*)d_in[8];
    const float* g2      = (const float*)d_in[9];
    const float* beta2   = (const float*)d_in[10];
    float* out = (float*)d_out;

    char* ws = (char*)d_ws;
    // Hpln (M x 1024 bf16) dead after kan1_gemm; Gonly aliases it.
    unsigned short* Hpln  = (unsigned short*)ws;
    unsigned short* Gonly = (unsigned short*)ws;                        // 33,554,432 B
    char* p1 = ws + (size_t)MTOT * HIDN * 2;
    unsigned short* y1   = (unsigned short*)p1;                         // 33,554,432 B
    unsigned short* y2   = (unsigned short*)p1;                         // alias (16 MB)
    char* p2 = p1 + (size_t)MTOT * HIDN * 2;
    unsigned short* W1T  = (unsigned short*)p2;                         // 1024*2048*2 = 4 MB
    char* p3 = p2 + (size_t)HIDN * KT1H * 2;
    unsigned short* W2T  = (unsigned short*)p3;                         // 512*3072*2 = 3 MB
    char* p4 = p3 + (size_t)OUTN * KTOT * 2;
    float* b1e = (float*)p4;
    float* b2e = (float*)(p4 + HIDN * sizeof(float));
    char* p5 = p4 + (HIDN + OUTN) * sizeof(float);
    unsigned short* xT   = (unsigned short*)p5;                         // 2,097,152 B
    char* p6 = p5 + (size_t)MTOT * CIN * 2;
    unsigned short* WinT = (unsigned short*)p6;                         // 131,072 B
    char* p7 = p6 + (size_t)HIDN * CIN * 2;
    unsigned short* WC1  = (unsigned short*)p7;                         // 131,072 B
    float* partial = (float*)W1T;    // alias: W1T dead after kan1_gemm (needs 1 MB)

    prep_all<<<1808, 256, 0, stream>>>(coeffs1, bias1, coeffs2, bias2, x, Win,
                                       W1T, b1e, W2T, b2e, xT, WinT);
    wc1_kernel<<<HIDN, 256, 0, stream>>>(coeffs1, WinT, bin, WC1, b1e);
    proj_mfma<<<dim3(MTOT / 128, HIDN / 128), 256, 0, stream>>>(xT, WinT, bin, Hpln);
    kan1_gemm<<<dim3(MTOT / 128, HIDN / 128), 256, 0, stream>>>(Hpln, xT, W1T, WC1, b1e, y1);
    ln_gelu<<<MTOT / 2, 256, 0, stream>>>(y1, g1, beta1, Gonly);
    kan2_gemm<<<dim3(MTOT / 128, OUTN / 128), 256, 0, stream>>>(Gonly, W2T, b2e, y2);
    ln_pool_partial<<<dim3(Bsz, LCHUNKS), 256, 0, stream>>>(y2, g2, beta2, partial);
    pool_reduce<<<Bsz, 256, 0, stream>>>(partial, out);
}